// Round 4
// baseline (910.450 us; speedup 1.0000x reference)
//
#include <hip/hip_runtime.h>

// ---------------------------------------------------------------------------
// Talking-heads transformer, 4 layers, f32 in/out (bf16 MFMA inside), gfx950.
// B=8 N=512 DIM=768 H=12 DH=64 MLP=3072 DEPTH=4 LS=0.1 EPS=1e-5
//
// BIG-WS layout (needs 151 MB; harness poison-fill shows ws = 256 MiB):
//   xf    f32  [4096,768]    @ 0          residual accumulator
//   h     bf16 [4096,768]    @ 12582912   LN out; also partial plane P0
//   qkv   bf16 [4096,2304]   @ 18874368   q|k|v; P1(W2)
//   S     bf16 [96,512,512]  @ 37748736   ALL attn scores; MLP mid; P1(Wo)
//   WtAll bf16 [4*7077888]   @ 88080384   all transposed weights, all layers
//   oP    bf16 [96,512,64]   @ 144703488  attention output, PLANAR per (b,g)
// Fallback (ws < 151 MB): previous 67.6 MB two-chunk layout.
// ---------------------------------------------------------------------------

#define LSCALE 0.1f

typedef __bf16 bf16;
typedef __bf16 bf16x8 __attribute__((ext_vector_type(8)));
typedef __bf16 bf16x4 __attribute__((ext_vector_type(4)));
typedef unsigned short ushort4v __attribute__((ext_vector_type(4)));
typedef float  f32x4  __attribute__((ext_vector_type(4)));

// async global->LDS, 16B/lane; LDS dest = wave-uniform base + lane*16B.
__device__ __forceinline__ void g2l16(const void* g, void* l) {
    __builtin_amdgcn_global_load_lds(
        (const __attribute__((address_space(1))) void*)g,
        (__attribute__((address_space(3))) void*)l, 16, 0, 0);
}

// ---------------------------------------------------------------------------
// GEMM (Bt form): C[M,N] = A[M,K] @ Bt[N,K]^T   (A,Bt bf16, g2l16 staging)
// BK=64 (two 32-k halves per barrier). N % 128 == 0, M % 128 == 0, K % 64 == 0.
// Epilogue: EPI 0 C=acc*scale | EPI 1 C=gelu(acc+bias) | EPI 4 C=acc (partial)
// PLANA: A is planar o [12 g][4096 m][64 d]; per block this is linear lda=64
//        with a (k0>>6)*32768 plane offset per K-tile (g2l16 path unchanged).
// C staged through LDS (128x136 bf16) for full-line coalesced 16B stores.
// split-K via z: z1=z/zmod, z2=z%zmod; saz2/sbz2 = k-offsets, scz2 = C offset.
// ---------------------------------------------------------------------------
template<int EPI, bool PLANA = false>
__global__ __launch_bounds__(256, 2)
void gemm_bt(const bf16* __restrict__ A, int lda, long saz1, long saz2,
             const bf16* __restrict__ Bt, int ldb, long sbz1, long sbz2,
             void* __restrict__ Cv, int ldc, long scz1, long scz2,
             int M, int N, int K, int zmod,
             const float* __restrict__ bias, float scale)
{
    __shared__ __align__(16) char smem[35840];   // staging 32KB | bounce 34.8KB
    bf16* As = (bf16*)smem;                      // [2][128*32]
    bf16* Bs = (bf16*)(smem + 16384);            // [2][128*32]
    bf16* Cs = (bf16*)smem;                      // [128][136] (aliases staging)

    const int z  = blockIdx.z;
    const int z1 = z / zmod, z2 = z - z1 * zmod;
    const bf16* Ab = A  + saz1 * (long)z1 + saz2 * (long)z2;
    const bf16* Bb = Bt + sbz1 * (long)z1 + sbz2 * (long)z2;

    const int m0 = blockIdx.x * 128, n0 = blockIdx.y * 128;
    const int tid = threadIdx.x, w = tid >> 6, l = tid & 63;
    const int wr = (w >> 1) * 64, wc = (w & 1) * 64;
    const int lr = l & 15, lq = l >> 4;
    const int srow = l >> 2, scol8 = (l & 3) * 8;

    long abase = 0;
    if constexpr (PLANA)
        abase = (long)(m0 >> 9) * 393216 + (long)((m0 & 511) + w * 32) * 64;

    f32x4 acc[4][4];
#pragma unroll
    for (int i = 0; i < 4; i++)
#pragma unroll
        for (int j = 0; j < 4; j++)
#pragma unroll
            for (int r = 0; r < 4; r++) acc[i][j][r] = 0.f;

    for (int k0 = 0; k0 < K; k0 += 64) {
        const bf16* Ag;
        int ldaa;
        if constexpr (PLANA) {
            Ag = Ab + abase + ((long)(k0 >> 6)) * 32768;
            ldaa = 64;
        } else {
            Ag = Ab + (long)(m0 + w * 32) * lda + k0;
            ldaa = lda;
        }
        const bf16* Bg = Bb + (long)(n0 + w * 32) * ldb + k0;
        g2l16(Ag + (long)srow * ldaa + scol8,             As + w * 1024);
        g2l16(Ag + (long)(srow + 16) * ldaa + scol8,      As + w * 1024 + 512);
        g2l16(Ag + (long)srow * ldaa + 32 + scol8,        As + 4096 + w * 1024);
        g2l16(Ag + (long)(srow + 16) * ldaa + 32 + scol8, As + 4096 + w * 1024 + 512);
        g2l16(Bg + (long)srow * ldb + scol8,             Bs + w * 1024);
        g2l16(Bg + (long)(srow + 16) * ldb + scol8,      Bs + w * 1024 + 512);
        g2l16(Bg + (long)srow * ldb + 32 + scol8,        Bs + 4096 + w * 1024);
        g2l16(Bg + (long)(srow + 16) * ldb + 32 + scol8, Bs + 4096 + w * 1024 + 512);
        __syncthreads();

#pragma unroll
        for (int hh = 0; hh < 2; hh++) {
            bf16x8 fa[4], fb[4];
#pragma unroll
            for (int i = 0; i < 4; i++)
                fa[i] = *(const bf16x8*)(As + hh * 4096 + (wr + i * 16 + lr) * 32 + lq * 8);
#pragma unroll
            for (int i = 0; i < 4; i++)
                fb[i] = *(const bf16x8*)(Bs + hh * 4096 + (wc + i * 16 + lr) * 32 + lq * 8);
#pragma unroll
            for (int mi = 0; mi < 4; mi++)
#pragma unroll
                for (int ni = 0; ni < 4; ni++)
                    acc[mi][ni] = __builtin_amdgcn_mfma_f32_16x16x32_bf16(
                        fa[mi], fb[ni], acc[mi][ni], 0, 0, 0);
        }
        __syncthreads();
    }

    // ---- epilogue: transform, bounce through LDS, coalesced 16B stores ----
#pragma unroll
    for (int ni = 0; ni < 4; ni++) {
        const int col = wc + ni * 16 + lr;
        float bv = 0.f;
        if (EPI == 1) bv = bias[n0 + col];
#pragma unroll
        for (int mi = 0; mi < 4; mi++) {
#pragma unroll
            for (int r = 0; r < 4; r++) {
                const int row = wr + mi * 16 + lq * 4 + r;
                float v = acc[mi][ni][r];
                if (EPI == 0) {
                    v *= scale;
                } else if (EPI == 1) {
                    const float xx = v + bv;
                    const float u  = 0.7978845608f * (xx + 0.044715f * xx * xx * xx);
                    const float th = 1.f - 2.f / (__expf(2.f * u) + 1.f);
                    v = 0.5f * xx * (1.f + th);
                }
                Cs[row * 136 + col] = (bf16)v;
            }
        }
    }
    __syncthreads();

    const long cb = scz1 * (long)z1 + scz2 * (long)z2;
    const int rrow = tid >> 4, cg = tid & 15;
#pragma unroll
    for (int p = 0; p < 8; p++) {
        const int row = p * 16 + rrow;
        const bf16x8 v = *(const bf16x8*)(Cs + row * 136 + cg * 8);
        *(bf16x8*)((bf16*)Cv + cb + (long)(m0 + row) * ldc + n0 + cg * 8) = v;
    }
}

// ---------------------------------------------------------------------------
// AV GEMM: o[b, i, g, d] = sum_j P[b,g,i,j] * v[b,j,g*64+d]
// One block: i-tile 64 x d 64, 4 waves stacked along i (16 rows each).
// PLANO=1: write planar o [z=(b,g)][512 i][64 d] via LDS bounce.
// PLANO=0 (fallback path): legacy scalar store into qkv q-slot.
// ---------------------------------------------------------------------------
template<int PLANO>
__global__ __launch_bounds__(256, 4)
void gemm_av(const bf16* __restrict__ S, const bf16* __restrict__ qkvc,
             bf16* __restrict__ oc)
{
    __shared__ __align__(16) char av_smem[9728];
    bf16* As  = (bf16*)av_smem;             // [64*32]  4096 B
    bf16* Bst = (bf16*)(av_smem + 4096);    // [64*40]  5120 B
    bf16* Cs  = (bf16*)av_smem;             // [64][68] 8704 B (aliases)

    const int z = blockIdx.y, b = z / 12, g = z - b * 12;
    const bf16* Ab = S + (long)z * 262144;
    const bf16* Bb = qkvc + (long)b * 1179648 + 1536 + g * 64;  // v

    const int i0 = blockIdx.x * 64;
    const int tid = threadIdx.x, w = tid >> 6, l = tid & 63;
    const int lr = l & 15, lq = l >> 4;
    const int srow = l >> 2, scol8 = (l & 3) * 8;
    const int kp = tid >> 4, dq = tid & 15;   // j-pair, d-quad
    const int kcol = ((((kp >> 2) ^ ((dq >> 1) & 3)) << 3) | ((kp & 3) << 1));

    f32x4 acc[4];
#pragma unroll
    for (int j = 0; j < 4; j++)
#pragma unroll
        for (int r = 0; r < 4; r++) acc[j][r] = 0.f;

    unsigned short* Bw = (unsigned short*)Bst;

    for (int k0 = 0; k0 < 512; k0 += 32) {
        const bf16* Ag = Ab + (long)(i0 + w * 16) * 512 + k0;
        g2l16(Ag + (long)srow * 512 + scol8, As + w * 512);

        const bf16* Bg = Bb + (long)(k0 + 2 * kp) * 2304 + dq * 4;
        ushort4v u0 = *(const ushort4v*)(Bg);
        ushort4v u1 = *(const ushort4v*)(Bg + 2304);
#pragma unroll
        for (int r = 0; r < 4; r++) {
            unsigned p = (unsigned)u0[r] | ((unsigned)u1[r] << 16);
            *(unsigned*)(Bw + (dq * 4 + r) * 40 + kcol) = p;
        }
        __syncthreads();

        bf16x8 fa = *(const bf16x8*)(As + (w * 16 + lr) * 32 + lq * 8);
        bf16x8 fb[4];
#pragma unroll
        for (int i = 0; i < 4; i++) {
            const int d = i * 16 + lr;
            fb[i] = *(const bf16x8*)(Bst + d * 40 + ((lq ^ ((d >> 3) & 3)) << 3));
        }
#pragma unroll
        for (int ni = 0; ni < 4; ni++)
            acc[ni] = __builtin_amdgcn_mfma_f32_16x16x32_bf16(
                fa, fb[ni], acc[ni], 0, 0, 0);
        __syncthreads();
    }

    if constexpr (PLANO) {
#pragma unroll
        for (int ni = 0; ni < 4; ni++)
#pragma unroll
            for (int r = 0; r < 4; r++)
                Cs[(w * 16 + lq * 4 + r) * 68 + ni * 16 + lr] = (bf16)acc[ni][r];
        __syncthreads();
        const int rr = tid >> 2, c16 = (tid & 3) * 16;
        bf16* orow = oc + ((long)z * 512 + i0 + rr) * 64 + c16;
        *(bf16x8*)(orow)     = *(const bf16x8*)(Cs + rr * 68 + c16);
        *(bf16x8*)(orow + 8) = *(const bf16x8*)(Cs + rr * 68 + c16 + 8);
    } else {
        bf16* Cb = oc + (long)b * 1179648 + g * 64;
#pragma unroll
        for (int ni = 0; ni < 4; ni++) {
            const int gc = ni * 16 + lr;
#pragma unroll
            for (int r = 0; r < 4; r++) {
                const int gr = i0 + w * 16 + lq * 4 + r;
                Cb[(long)gr * 2304 + gc] = (bf16)acc[ni][r];
            }
        }
    }
}

// ---------------------------------------------------------------------------
// transpose+convert: in f32 [K,N] -> out bf16 [N,K].  32x32 tiles.
// (fallback path only)
// ---------------------------------------------------------------------------
__global__ __launch_bounds__(256)
void tconv_k(const float* __restrict__ in, bf16* __restrict__ out,
             int K, int N)
{
    __shared__ float t[32][33];
    const int n0 = blockIdx.x * 32, k0 = blockIdx.y * 32;
    const int x = threadIdx.x, y = threadIdx.y;
#pragma unroll
    for (int yy = 0; yy < 4; yy++)
        t[y + yy * 8][x] = in[(long)(k0 + y + yy * 8) * N + n0 + x];
    __syncthreads();
#pragma unroll
    for (int yy = 0; yy < 4; yy++)
        out[(long)(n0 + y + yy * 8) * K + k0 + x] = (bf16)t[x][y + yy * 8];
}

// ---------------------------------------------------------------------------
// pre_k: heterogeneous-block co-schedule of
//   blocks [0, 6912):      ALL weight transposes (64x64 tiles, v2 geometry —
//                          tconv is HBM/latency-pinned at ~2.2 TB/s regardless
//                          of pattern, so overlap it with independent work)
//   blocks [6912, 11008):  L0 lnres (xf <- x, h = LN(x)*ln1) — independent.
// ---------------------------------------------------------------------------
__global__ __launch_bounds__(256)
void pre_k(const float* __restrict__ Wq, const float* __restrict__ Wkv,
           const float* __restrict__ Wo, const float* __restrict__ W1,
           const float* __restrict__ W2, bf16* __restrict__ WtAll,
           const float* __restrict__ x, float* __restrict__ xf,
           const float* __restrict__ gam, bf16* __restrict__ hout)
{
    __shared__ __align__(16) char pmem[16640];
    const int bxg = blockIdx.x;
    const int t = threadIdx.x;
    if (bxg < 6912) {
        float (*st)[65] = (float(*)[65])pmem;
        const int L = bxg / 1728;
        int bx = bxg - L * 1728;
        bf16* WtL = WtAll + (long)L * 7077888;
        const float* src; bf16* dst; int K, N, ntn;
        if (bx < 144) {
            src = Wq + (long)L * 589824;   dst = WtL;            K = 768;  N = 768;  ntn = 12;
        } else if (bx < 432) {
            bx -= 144;
            src = Wkv + (long)L * 1179648; dst = WtL + 589824;   K = 768;  N = 1536; ntn = 24;
        } else if (bx < 576) {
            bx -= 432;
            src = Wo + (long)L * 589824;   dst = WtL + 1769472;  K = 768;  N = 768;  ntn = 12;
        } else if (bx < 1152) {
            bx -= 576;
            src = W1 + (long)L * 2359296;  dst = WtL + 2359296;  K = 768;  N = 3072; ntn = 48;
        } else {
            bx -= 1152;
            src = W2 + (long)L * 2359296;  dst = WtL + 4718592;  K = 3072; N = 768;  ntn = 12;
        }
        const int n0 = (bx % ntn) * 64, k0 = (bx / ntn) * 64;
        const int r = t >> 4, c4 = (t & 15) * 4;
#pragma unroll
        for (int rr = 0; rr < 4; rr++) {
            const f32x4 v = *(const f32x4*)(src + (long)(k0 + r + rr * 16) * N + n0 + c4);
            st[r + rr * 16][c4 + 0] = v[0];
            st[r + rr * 16][c4 + 1] = v[1];
            st[r + rr * 16][c4 + 2] = v[2];
            st[r + rr * 16][c4 + 3] = v[3];
        }
        __syncthreads();
        const int kc = (t & 7) * 8;
#pragma unroll
        for (int p = 0; p < 2; p++) {
            const int n = p * 32 + (t >> 3);
            bf16x8 o;
#pragma unroll
            for (int e = 0; e < 8; e++) o[e] = (bf16)st[kc + e][n];
            *(bf16x8*)(dst + (long)(n0 + n) * K + k0 + kc) = o;
        }
    } else {
        const int row = bxg - 6912;
        float* ps  = (float*)pmem;       // [4]
        float* pss = (float*)pmem + 4;   // [4]
        const float* xin = x + (long)row * 768;
        float* xr = xf + (long)row * 768;
        float v[3];
#pragma unroll
        for (int i = 0; i < 3; i++) {
            const int c = t + i * 256;
            const float xv = xin[c];
            xr[c] = xv;
            v[i] = xv;
        }
        float s  = v[0] + v[1] + v[2];
        float ss = v[0] * v[0] + v[1] * v[1] + v[2] * v[2];
#pragma unroll
        for (int off = 32; off; off >>= 1) {
            s  += __shfl_xor(s, off);
            ss += __shfl_xor(ss, off);
        }
        const int wv = t >> 6, l = t & 63;
        if (l == 0) { ps[wv] = s; pss[wv] = ss; }
        __syncthreads();
        s  = ps[0] + ps[1] + ps[2] + ps[3];
        ss = pss[0] + pss[1] + pss[2] + pss[3];
        const float mu = s * (1.f / 768.f);
        const float rs = rsqrtf(ss * (1.f / 768.f) - mu * mu + 1e-5f);
        bf16* orow = hout + (long)row * 768;
#pragma unroll
        for (int i = 0; i < 3; i++) {
            const int c = t + i * 256;
            orow[c] = (bf16)((v[i] - mu) * rs * gam[c]);
        }
    }
}

// ---------------------------------------------------------------------------
// Fused residual-reduce + LayerNorm.
// src != null (L0): xf <- src, h = LN(src)
// P0 != null:       xf += LS*(P0+P1+bias), h = LN(xf)
// ---------------------------------------------------------------------------
__global__ __launch_bounds__(256)
void lnres_k(float* __restrict__ xf, const bf16* __restrict__ P0,
             const bf16* __restrict__ P1, const float* __restrict__ bias,
             const float* __restrict__ gam, bf16* __restrict__ out,
             const float* __restrict__ src)
{
    const int row = blockIdx.x, t = threadIdx.x;
    float* xr = xf + (long)row * 768;
    float v[3];
#pragma unroll
    for (int i = 0; i < 3; i++) {
        const int c = t + i * 256;
        float xv;
        if (src) {
            xv = src[(long)row * 768 + c];
            xr[c] = xv;
        } else if (P0) {
            xv = xr[c] + LSCALE * ((float)P0[(long)row * 768 + c] +
                                   (float)P1[(long)row * 768 + c] + bias[c]);
            xr[c] = xv;
        } else {
            xv = xr[c];
        }
        v[i] = xv;
    }
    float s  = v[0] + v[1] + v[2];
    float ss = v[0] * v[0] + v[1] * v[1] + v[2] * v[2];
#pragma unroll
    for (int off = 32; off; off >>= 1) {
        s  += __shfl_xor(s, off);
        ss += __shfl_xor(ss, off);
    }
    __shared__ float ps[4], pss[4];
    const int wv = t >> 6, l = t & 63;
    if (l == 0) { ps[wv] = s; pss[wv] = ss; }
    __syncthreads();
    s  = ps[0] + ps[1] + ps[2] + ps[3];
    ss = pss[0] + pss[1] + pss[2] + pss[3];
    const float mu = s * (1.f / 768.f);
    const float rs = rsqrtf(ss * (1.f / 768.f) - mu * mu + 1e-5f);
    bf16* orow = out + (long)row * 768;
#pragma unroll
    for (int i = 0; i < 3; i++) {
        const int c = t + i * 256;
        orow[c] = (bf16)((v[i] - mu) * rs * gam[c]);
    }
}

// final: d_out = xf + LS*(P0 + P1 + bias)   (f32 out), 4 elems/thread
__global__ __launch_bounds__(256)
void outres_k(const float* __restrict__ xf, const bf16* __restrict__ P0,
              const bf16* __restrict__ P1, const float* __restrict__ bias,
              float* __restrict__ out)
{
    const long i4 = ((long)blockIdx.x * 256 + threadIdx.x) * 4;
    const int c = (int)(i4 % 768);
    const f32x4 xv = *(const f32x4*)(xf + i4);
    const bf16x4 p0 = *(const bf16x4*)(P0 + i4);
    const bf16x4 p1 = *(const bf16x4*)(P1 + i4);
    const f32x4 bv = *(const f32x4*)(bias + c);
    f32x4 o;
#pragma unroll
    for (int e = 0; e < 4; e++)
        o[e] = xv[e] + LSCALE * ((float)p0[e] + (float)p1[e] + bv[e]);
    *(f32x4*)(out + i4) = o;
}

// ---------------------------------------------------------------------------
// talking-heads mix (pre) -> softmax -> mix (post), in place on S
// [nb,12,512,512].  v2: block = (b, 4 rows), one WAVE per row.
// 16 B/lane loads/stores (vs 4 B/lane before); premix+softmax+postmix fully
// in registers; row-reduce = shfl_xor across the owning wave; zero LDS.
// Accumulation order (h ascending) identical to v1 -> numerics unchanged.
// ---------------------------------------------------------------------------
__global__ __launch_bounds__(256)
void mixsm_k(bf16* __restrict__ S, const float* __restrict__ mp,
             const float* __restrict__ mq)
{
    const int b = blockIdx.y, i4 = blockIdx.x, t = threadIdx.x;
    const int w = t >> 6, l = t & 63;
    const int row = i4 * 4 + w;
    bf16* Sb = S + ((long)b * 12 * 512 + row) * 512 + l * 8;

    float a[12][8];
#pragma unroll
    for (int g = 0; g < 12; g++)
#pragma unroll
        for (int e = 0; e < 8; e++) a[g][e] = 0.f;

    // load + pre-mix (h ascending accumulation, matches v1 order)
#pragma unroll
    for (int h = 0; h < 12; h++) {
        const bf16x8 sv = *(const bf16x8*)(Sb + (long)h * 262144);
        float f[8];
#pragma unroll
        for (int e = 0; e < 8; e++) f[e] = (float)sv[e];
#pragma unroll
        for (int g = 0; g < 12; g++) {
            const float m = mp[h * 12 + g];     // uniform -> SGPR
#pragma unroll
            for (int e = 0; e < 8; e++) a[g][e] += f[e] * m;
        }
    }

    // softmax along j (row = this wave: 64 lanes x 8 elems)
#pragma unroll
    for (int g = 0; g < 12; g++) {
        float mx = a[g][0];
#pragma unroll
        for (int e = 1; e < 8; e++) mx = fmaxf(mx, a[g][e]);
#pragma unroll
        for (int off = 32; off; off >>= 1) mx = fmaxf(mx, __shfl_xor(mx, off));
        float sm = 0.f;
#pragma unroll
        for (int e = 0; e < 8; e++) {
            const float ev = __expf(a[g][e] - mx);
            a[g][e] = ev;
            sm += ev;
        }
#pragma unroll
        for (int off = 32; off; off >>= 1) sm += __shfl_xor(sm, off);
        const float rd = 1.f / sm;
#pragma unroll
        for (int e = 0; e < 8; e++) a[g][e] *= rd;
    }

    // post-mix in two g-halves (caps live VGPRs), 16 B/lane stores
#pragma unroll
    for (int hf = 0; hf < 2; hf++) {
        float o[6][8];
#pragma unroll
        for (int gg = 0; gg < 6; gg++)
#pragma unroll
            for (int e = 0; e < 8; e++) o[gg][e] = 0.f;
#pragma unroll
        for (int h = 0; h < 12; h++) {
#pragma unroll
            for (int gg = 0; gg < 6; gg++) {
                const float m = mq[h * 12 + hf * 6 + gg];   // uniform -> SGPR
#pragma unroll
                for (int e = 0; e < 8; e++) o[gg][e] += a[h][e] * m;
            }
        }
#pragma unroll
        for (int gg = 0; gg < 6; gg++) {
            bf16x8 ov;
#pragma unroll
            for (int e = 0; e < 8; e++) ov[e] = (bf16)o[gg][e];
            *(bf16x8*)(Sb + (long)(hf * 6 + gg) * 262144) = ov;
        }
    }
}

// ---------------------------------------------------------------------------
extern "C" void kernel_launch(void* const* d_in, const int* in_sizes, int n_in,
                              void* d_out, int out_size, void* d_ws, size_t ws_size,
                              hipStream_t stream)
{
    (void)in_sizes; (void)n_in; (void)out_size;
    const float* x   = (const float*)d_in[0];
    const float* ln1 = (const float*)d_in[1];
    const float* Wq  = (const float*)d_in[2];
    const float* Wkv = (const float*)d_in[3];
    const float* mp  = (const float*)d_in[4];
    const float* mq  = (const float*)d_in[5];
    const float* Wo  = (const float*)d_in[6];
    const float* bo  = (const float*)d_in[7];
    const float* ln2 = (const float*)d_in[8];
    const float* W1  = (const float*)d_in[9];
    const float* b1  = (const float*)d_in[10];
    const float* W2  = (const float*)d_in[11];
    const float* b2  = (const float*)d_in[12];

    char* ws = (char*)d_ws;
    float* xf  = (float*)(ws);               // [4096,768] f32
    bf16* h    = (bf16*)(ws + 12582912);     // [4096,768]; partial plane P0
    bf16* qkv  = (bf16*)(ws + 18874368);     // [4096,2304]; P1(W2)
    bf16* S    = (bf16*)(ws + 37748736);     // scores; MLP mid; P1(Wo)
    bf16* mid  = S;
    bf16* P0   = h;
    bf16* P1w2 = qkv;
    bf16* P1wo = S;
    const long P1W2_OFF = 3145728;           // (qkv - h) in elements
    const long P1WO_OFF = 12582912;          // (S - h) in elements

    const dim3 tb(32, 8);

    if (ws_size >= 150994944ull) {
        // ============ big-workspace path ===================================
        bf16* WtAll = (bf16*)(ws + 88080384);  // [4][7077888]
        bf16* oP    = (bf16*)(ws + 144703488); // [96][512][64] planar attn-o

        // weight transposes (6912 blocks) || L0 lnres (4096 blocks)
        pre_k<<<11008, 256, 0, stream>>>(Wq, Wkv, Wo, W1, W2, WtAll,
                                         x, xf, ln1, h);

        for (int L = 0; L < 4; L++) {
            bf16* WtL = WtAll + (long)L * 7077888;

            // x += LS*(prev-W2 partials + b2_{L-1}) [L>0]; h = LN(x)*ln1
            if (L > 0)
                lnres_k<<<4096, 256, 0, stream>>>(xf, P0, P1w2, b2 + (L - 1) * 768,
                                                  ln1 + L * 768, h, nullptr);

            // qkv = h @ [Wq | Wkv]
            gemm_bt<0><<<dim3(32, 18, 1), 256, 0, stream>>>(
                h, 768, 0, 0, WtL, 768, 0, 0,
                qkv, 2304, 0, 0, 4096, 2304, 768, 1, nullptr, 1.f);

            // scores for ALL 8 batches x 12 heads in one launch
            gemm_bt<0><<<dim3(4, 4, 96), 256, 0, stream>>>(
                qkv,       2304, 1179648, 64,
                qkv + 768, 2304, 1179648, 64,
                S,          512, 3145728, 262144,
                512, 512, 64, 12, nullptr, 0.125f);

            mixsm_k<<<dim3(128, 8), 256, 0, stream>>>(S, mp + L * 144, mq + L * 144);

            // o (planar) = attn @ v, all planes
            gemm_av<1><<<dim3(8, 96), 256, 0, stream>>>(S, qkv, oP);

            // Wo partials: P0/P1wo = o @ Wo (split-K=2, planar A)
            gemm_bt<4, true><<<dim3(32, 6, 2), 256, 0, stream>>>(
                oP, 64, 0, 196608, WtL + 1769472, 768, 0, 384,
                P0, 768, 0, P1WO_OFF, 4096, 768, 384, 2, nullptr, 1.f);

            // x += LS*(P0+P1+bo); h = LN(x)*ln2
            lnres_k<<<4096, 256, 0, stream>>>(xf, P0, P1wo, bo + L * 768,
                                              ln2 + L * 768, h, nullptr);

            // mid = gelu(h @ W1 + b1)
            gemm_bt<1><<<dim3(32, 24, 1), 256, 0, stream>>>(
                h, 768, 0, 0, WtL + 2359296, 768, 0, 0,
                mid, 3072, 0, 0, 4096, 3072, 768, 1, b1 + L * 3072, 1.f);

            // W2 partials: P0/P1w2 = mid @ W2 (split-K=2)
            gemm_bt<4><<<dim3(32, 6, 2), 256, 0, stream>>>(
                mid, 3072, 0, 1536, WtL + 4718592, 3072, 0, 1536,
                P0, 768, 0, P1W2_OFF, 4096, 768, 1536, 2, nullptr, 1.f);
        }
    } else {
        // ============ fallback: previous 67.6 MB two-chunk path ============
        bf16* Wt = (bf16*)(ws + 62914560);

        for (int L = 0; L < 4; L++) {
            tconv_k<<<dim3(24, 24), tb, 0, stream>>>(Wq + (long)L * 589824, Wt, 768, 768);
            tconv_k<<<dim3(48, 24), tb, 0, stream>>>(Wkv + (long)L * 1179648, Wt + 589824, 768, 1536);

            if (L == 0)
                lnres_k<<<4096, 256, 0, stream>>>(xf, nullptr, nullptr, nullptr,
                                                  ln1 + L * 768, h, x);
            else
                lnres_k<<<4096, 256, 0, stream>>>(xf, P0, P1w2, b2 + (L - 1) * 768,
                                                  ln1 + L * 768, h, nullptr);

            gemm_bt<0><<<dim3(32, 18, 1), 256, 0, stream>>>(
                h, 768, 0, 0, Wt, 768, 0, 0,
                qkv, 2304, 0, 0, 4096, 2304, 768, 1, nullptr, 1.f);

            for (int c = 0; c < 2; c++) {
                const long qb = (long)c * 4718592;
                gemm_bt<0><<<dim3(4, 4, 48), 256, 0, stream>>>(
                    qkv + qb,       2304, 1179648, 64,
                    qkv + 768 + qb, 2304, 1179648, 64,
                    S,               512, 3145728, 262144,
                    512, 512, 64, 12, nullptr, 0.125f);

                mixsm_k<<<dim3(128, 4), 256, 0, stream>>>(S, mp + L * 144, mq + L * 144);

                gemm_av<0><<<dim3(8, 48), 256, 0, stream>>>(S, qkv + qb, qkv + qb);
            }

            tconv_k<<<dim3(24, 24), tb, 0, stream>>>(Wo + (long)L * 589824, Wt, 768, 768);
            gemm_bt<4><<<dim3(32, 6, 2), 256, 0, stream>>>(
                qkv, 2304, 0, 384, Wt, 768, 0, 384,
                P0, 768, 0, P1WO_OFF, 4096, 768, 384, 2, nullptr, 1.f);

            lnres_k<<<4096, 256, 0, stream>>>(xf, P0, P1wo, bo + L * 768,
                                              ln2 + L * 768, h, nullptr);

            tconv_k<<<dim3(96, 24), tb, 0, stream>>>(W1 + (long)L * 2359296, Wt, 768, 3072);
            gemm_bt<1><<<dim3(32, 24, 1), 256, 0, stream>>>(
                h, 768, 0, 0, Wt, 768, 0, 0,
                mid, 3072, 0, 0, 4096, 3072, 768, 1, b1 + L * 3072, 1.f);

            tconv_k<<<dim3(24, 96), tb, 0, stream>>>(W2 + (long)L * 2359296, Wt, 3072, 768);
            gemm_bt<4><<<dim3(32, 6, 2), 256, 0, stream>>>(
                mid, 3072, 0, 1536, Wt, 3072, 0, 1536,
                P0, 768, 0, P1W2_OFF, 4096, 768, 1536, 2, nullptr, 1.f);
        }
    }

    // d_out = xf + LS*(P0+P1+b2_3)
    outres_k<<<3072, 256, 0, stream>>>(xf, P0, P1w2, b2 + 3 * 768, (float*)d_out);
}

// Round 5
// 872.281 us; speedup vs baseline: 1.0438x; 1.0438x over previous
//
#include <hip/hip_runtime.h>

// ---------------------------------------------------------------------------
// Talking-heads transformer, 4 layers, f32 in/out (bf16 MFMA inside), gfx950.
// B=8 N=512 DIM=768 H=12 DH=64 MLP=3072 DEPTH=4 LS=0.1 EPS=1e-5
//
// BIG-WS layout (needs 151 MB; harness poison-fill shows ws = 256 MiB):
//   xf    f32  [4096,768]    @ 0          residual accumulator
//   h     bf16 [4096,768]    @ 12582912   LN out; also partial plane P0
//   qkv   bf16 [4096,2304]   @ 18874368   q|k|v; P1(W2)
//   S     bf16 [8,512,12,512]@ 37748736   attn scores, HEAD-CONTIGUOUS layout
//                                         [b][i][h][j]; MLP mid; P1(Wo)
//   WtAll bf16 [4*7077888]   @ 88080384   all transposed weights, all layers
//   oP    bf16 [96,512,64]   @ 144703488  attention output, PLANAR per (b,g)
// Fallback (ws < 151 MB): previous 67.6 MB two-chunk layout (old S layout).
// ---------------------------------------------------------------------------

#define LSCALE 0.1f

typedef __bf16 bf16;
typedef __bf16 bf16x8 __attribute__((ext_vector_type(8)));
typedef __bf16 bf16x4 __attribute__((ext_vector_type(4)));
typedef unsigned short ushort4v __attribute__((ext_vector_type(4)));
typedef float  f32x4  __attribute__((ext_vector_type(4)));

// async global->LDS, 16B/lane; LDS dest = wave-uniform base + lane*16B.
__device__ __forceinline__ void g2l16(const void* g, void* l) {
    __builtin_amdgcn_global_load_lds(
        (const __attribute__((address_space(1))) void*)g,
        (__attribute__((address_space(3))) void*)l, 16, 0, 0);
}

// ---------------------------------------------------------------------------
// GEMM (Bt form): C[M,N] = A[M,K] @ Bt[N,K]^T   (A,Bt bf16, g2l16 staging)
// BK=64 (two 32-k halves per barrier). N % 128 == 0, M % 128 == 0, K % 64 == 0.
// Epilogue: EPI 0 C=acc*scale | EPI 1 C=gelu(acc+bias) | EPI 4 C=acc (partial)
// PLANA: A is planar o [12 g][4096 m][64 d]; per block this is linear lda=64
//        with a (k0>>6)*32768 plane offset per K-tile (g2l16 path unchanged).
// C staged through LDS (128x136 bf16) for full-line coalesced 16B stores.
// split-K via z: z1=z/zmod, z2=z%zmod; saz2/sbz2 = k-offsets, scz2 = C offset.
// ---------------------------------------------------------------------------
template<int EPI, bool PLANA = false>
__global__ __launch_bounds__(256, 2)
void gemm_bt(const bf16* __restrict__ A, int lda, long saz1, long saz2,
             const bf16* __restrict__ Bt, int ldb, long sbz1, long sbz2,
             void* __restrict__ Cv, int ldc, long scz1, long scz2,
             int M, int N, int K, int zmod,
             const float* __restrict__ bias, float scale)
{
    __shared__ __align__(16) char smem[35840];   // staging 32KB | bounce 34.8KB
    bf16* As = (bf16*)smem;                      // [2][128*32]
    bf16* Bs = (bf16*)(smem + 16384);            // [2][128*32]
    bf16* Cs = (bf16*)smem;                      // [128][136] (aliases staging)

    const int z  = blockIdx.z;
    const int z1 = z / zmod, z2 = z - z1 * zmod;
    const bf16* Ab = A  + saz1 * (long)z1 + saz2 * (long)z2;
    const bf16* Bb = Bt + sbz1 * (long)z1 + sbz2 * (long)z2;

    const int m0 = blockIdx.x * 128, n0 = blockIdx.y * 128;
    const int tid = threadIdx.x, w = tid >> 6, l = tid & 63;
    const int wr = (w >> 1) * 64, wc = (w & 1) * 64;
    const int lr = l & 15, lq = l >> 4;
    const int srow = l >> 2, scol8 = (l & 3) * 8;

    long abase = 0;
    if constexpr (PLANA)
        abase = (long)(m0 >> 9) * 393216 + (long)((m0 & 511) + w * 32) * 64;

    f32x4 acc[4][4];
#pragma unroll
    for (int i = 0; i < 4; i++)
#pragma unroll
        for (int j = 0; j < 4; j++)
#pragma unroll
            for (int r = 0; r < 4; r++) acc[i][j][r] = 0.f;

    for (int k0 = 0; k0 < K; k0 += 64) {
        const bf16* Ag;
        int ldaa;
        if constexpr (PLANA) {
            Ag = Ab + abase + ((long)(k0 >> 6)) * 32768;
            ldaa = 64;
        } else {
            Ag = Ab + (long)(m0 + w * 32) * lda + k0;
            ldaa = lda;
        }
        const bf16* Bg = Bb + (long)(n0 + w * 32) * ldb + k0;
        g2l16(Ag + (long)srow * ldaa + scol8,             As + w * 1024);
        g2l16(Ag + (long)(srow + 16) * ldaa + scol8,      As + w * 1024 + 512);
        g2l16(Ag + (long)srow * ldaa + 32 + scol8,        As + 4096 + w * 1024);
        g2l16(Ag + (long)(srow + 16) * ldaa + 32 + scol8, As + 4096 + w * 1024 + 512);
        g2l16(Bg + (long)srow * ldb + scol8,             Bs + w * 1024);
        g2l16(Bg + (long)(srow + 16) * ldb + scol8,      Bs + w * 1024 + 512);
        g2l16(Bg + (long)srow * ldb + 32 + scol8,        Bs + 4096 + w * 1024);
        g2l16(Bg + (long)(srow + 16) * ldb + 32 + scol8, Bs + 4096 + w * 1024 + 512);
        __syncthreads();

#pragma unroll
        for (int hh = 0; hh < 2; hh++) {
            bf16x8 fa[4], fb[4];
#pragma unroll
            for (int i = 0; i < 4; i++)
                fa[i] = *(const bf16x8*)(As + hh * 4096 + (wr + i * 16 + lr) * 32 + lq * 8);
#pragma unroll
            for (int i = 0; i < 4; i++)
                fb[i] = *(const bf16x8*)(Bs + hh * 4096 + (wc + i * 16 + lr) * 32 + lq * 8);
#pragma unroll
            for (int mi = 0; mi < 4; mi++)
#pragma unroll
                for (int ni = 0; ni < 4; ni++)
                    acc[mi][ni] = __builtin_amdgcn_mfma_f32_16x16x32_bf16(
                        fa[mi], fb[ni], acc[mi][ni], 0, 0, 0);
        }
        __syncthreads();
    }

    // ---- epilogue: transform, bounce through LDS, coalesced 16B stores ----
#pragma unroll
    for (int ni = 0; ni < 4; ni++) {
        const int col = wc + ni * 16 + lr;
        float bv = 0.f;
        if (EPI == 1) bv = bias[n0 + col];
#pragma unroll
        for (int mi = 0; mi < 4; mi++) {
#pragma unroll
            for (int r = 0; r < 4; r++) {
                const int row = wr + mi * 16 + lq * 4 + r;
                float v = acc[mi][ni][r];
                if (EPI == 0) {
                    v *= scale;
                } else if (EPI == 1) {
                    const float xx = v + bv;
                    const float u  = 0.7978845608f * (xx + 0.044715f * xx * xx * xx);
                    const float th = 1.f - 2.f / (__expf(2.f * u) + 1.f);
                    v = 0.5f * xx * (1.f + th);
                }
                Cs[row * 136 + col] = (bf16)v;
            }
        }
    }
    __syncthreads();

    const long cb = scz1 * (long)z1 + scz2 * (long)z2;
    const int rrow = tid >> 4, cg = tid & 15;
#pragma unroll
    for (int p = 0; p < 8; p++) {
        const int row = p * 16 + rrow;
        const bf16x8 v = *(const bf16x8*)(Cs + row * 136 + cg * 8);
        *(bf16x8*)((bf16*)Cv + cb + (long)(m0 + row) * ldc + n0 + cg * 8) = v;
    }
}

// ---------------------------------------------------------------------------
// AV GEMM: o[b, i, g, d] = sum_j P[b,g-plane,i,j] * v[b,j,g*64+d]
// One block: i-tile 64 x d 64, 4 waves stacked along i (16 rows each).
// PLANO=1: S in head-contiguous layout [b][i][g][j] (row stride 6144);
//          write planar o [z=(b,g)][512 i][64 d] via LDS bounce.
// PLANO=0 (fallback): S old layout [b][g][i][j]; scalar store into q-slot.
// ---------------------------------------------------------------------------
template<int PLANO>
__global__ __launch_bounds__(256, 4)
void gemm_av(const bf16* __restrict__ S, const bf16* __restrict__ qkvc,
             bf16* __restrict__ oc)
{
    __shared__ __align__(16) char av_smem[9728];
    bf16* As  = (bf16*)av_smem;             // [64*32]  4096 B
    bf16* Bst = (bf16*)(av_smem + 4096);    // [64*40]  5120 B
    bf16* Cs  = (bf16*)av_smem;             // [64][68] 8704 B (aliases)

    const int z = blockIdx.y, b = z / 12, g = z - b * 12;
    const bf16* Ab;
    int sld;
    if constexpr (PLANO) {
        Ab = S + (long)b * 3145728 + g * 512;   // [b][i][g][j]
        sld = 6144;
    } else {
        Ab = S + (long)z * 262144;              // [b][g][i][j]
        sld = 512;
    }
    const bf16* Bb = qkvc + (long)b * 1179648 + 1536 + g * 64;  // v

    const int i0 = blockIdx.x * 64;
    const int tid = threadIdx.x, w = tid >> 6, l = tid & 63;
    const int lr = l & 15, lq = l >> 4;
    const int srow = l >> 2, scol8 = (l & 3) * 8;
    const int kp = tid >> 4, dq = tid & 15;   // j-pair, d-quad
    const int kcol = ((((kp >> 2) ^ ((dq >> 1) & 3)) << 3) | ((kp & 3) << 1));

    f32x4 acc[4];
#pragma unroll
    for (int j = 0; j < 4; j++)
#pragma unroll
        for (int r = 0; r < 4; r++) acc[j][r] = 0.f;

    unsigned short* Bw = (unsigned short*)Bst;

    for (int k0 = 0; k0 < 512; k0 += 32) {
        const bf16* Ag = Ab + (long)(i0 + w * 16) * sld + k0;
        g2l16(Ag + (long)srow * sld + scol8, As + w * 512);

        const bf16* Bg = Bb + (long)(k0 + 2 * kp) * 2304 + dq * 4;
        ushort4v u0 = *(const ushort4v*)(Bg);
        ushort4v u1 = *(const ushort4v*)(Bg + 2304);
#pragma unroll
        for (int r = 0; r < 4; r++) {
            unsigned p = (unsigned)u0[r] | ((unsigned)u1[r] << 16);
            *(unsigned*)(Bw + (dq * 4 + r) * 40 + kcol) = p;
        }
        __syncthreads();

        bf16x8 fa = *(const bf16x8*)(As + (w * 16 + lr) * 32 + lq * 8);
        bf16x8 fb[4];
#pragma unroll
        for (int i = 0; i < 4; i++) {
            const int d = i * 16 + lr;
            fb[i] = *(const bf16x8*)(Bst + d * 40 + ((lq ^ ((d >> 3) & 3)) << 3));
        }
#pragma unroll
        for (int ni = 0; ni < 4; ni++)
            acc[ni] = __builtin_amdgcn_mfma_f32_16x16x32_bf16(
                fa, fb[ni], acc[ni], 0, 0, 0);
        __syncthreads();
    }

    if constexpr (PLANO) {
#pragma unroll
        for (int ni = 0; ni < 4; ni++)
#pragma unroll
            for (int r = 0; r < 4; r++)
                Cs[(w * 16 + lq * 4 + r) * 68 + ni * 16 + lr] = (bf16)acc[ni][r];
        __syncthreads();
        const int rr = tid >> 2, c16 = (tid & 3) * 16;
        bf16* orow = oc + ((long)z * 512 + i0 + rr) * 64 + c16;
        *(bf16x8*)(orow)     = *(const bf16x8*)(Cs + rr * 68 + c16);
        *(bf16x8*)(orow + 8) = *(const bf16x8*)(Cs + rr * 68 + c16 + 8);
    } else {
        bf16* Cb = oc + (long)b * 1179648 + g * 64;
#pragma unroll
        for (int ni = 0; ni < 4; ni++) {
            const int gc = ni * 16 + lr;
#pragma unroll
            for (int r = 0; r < 4; r++) {
                const int gr = i0 + w * 16 + lq * 4 + r;
                Cb[(long)gr * 2304 + gc] = (bf16)acc[ni][r];
            }
        }
    }
}

// ---------------------------------------------------------------------------
// transpose+convert: in f32 [K,N] -> out bf16 [N,K].  32x32 tiles.
// (fallback path only)
// ---------------------------------------------------------------------------
__global__ __launch_bounds__(256)
void tconv_k(const float* __restrict__ in, bf16* __restrict__ out,
             int K, int N)
{
    __shared__ float t[32][33];
    const int n0 = blockIdx.x * 32, k0 = blockIdx.y * 32;
    const int x = threadIdx.x, y = threadIdx.y;
#pragma unroll
    for (int yy = 0; yy < 4; yy++)
        t[y + yy * 8][x] = in[(long)(k0 + y + yy * 8) * N + n0 + x];
    __syncthreads();
#pragma unroll
    for (int yy = 0; yy < 4; yy++)
        out[(long)(n0 + y + yy * 8) * K + k0 + x] = (bf16)t[x][y + yy * 8];
}

// ---------------------------------------------------------------------------
// pre_k: heterogeneous-block co-schedule of
//   blocks [0, 6912):      ALL weight transposes (64x64 tiles; tconv is
//                          HBM/latency-pinned regardless of pattern, so
//                          overlap it with independent work)
//   blocks [6912, 11008):  L0 lnres (xf <- x, h = LN(x)*ln1) — independent.
// ---------------------------------------------------------------------------
__global__ __launch_bounds__(256)
void pre_k(const float* __restrict__ Wq, const float* __restrict__ Wkv,
           const float* __restrict__ Wo, const float* __restrict__ W1,
           const float* __restrict__ W2, bf16* __restrict__ WtAll,
           const float* __restrict__ x, float* __restrict__ xf,
           const float* __restrict__ gam, bf16* __restrict__ hout)
{
    __shared__ __align__(16) char pmem[16640];
    const int bxg = blockIdx.x;
    const int t = threadIdx.x;
    if (bxg < 6912) {
        float (*st)[65] = (float(*)[65])pmem;
        const int L = bxg / 1728;
        int bx = bxg - L * 1728;
        bf16* WtL = WtAll + (long)L * 7077888;
        const float* src; bf16* dst; int K, N, ntn;
        if (bx < 144) {
            src = Wq + (long)L * 589824;   dst = WtL;            K = 768;  N = 768;  ntn = 12;
        } else if (bx < 432) {
            bx -= 144;
            src = Wkv + (long)L * 1179648; dst = WtL + 589824;   K = 768;  N = 1536; ntn = 24;
        } else if (bx < 576) {
            bx -= 432;
            src = Wo + (long)L * 589824;   dst = WtL + 1769472;  K = 768;  N = 768;  ntn = 12;
        } else if (bx < 1152) {
            bx -= 576;
            src = W1 + (long)L * 2359296;  dst = WtL + 2359296;  K = 768;  N = 3072; ntn = 48;
        } else {
            bx -= 1152;
            src = W2 + (long)L * 2359296;  dst = WtL + 4718592;  K = 3072; N = 768;  ntn = 12;
        }
        const int n0 = (bx % ntn) * 64, k0 = (bx / ntn) * 64;
        const int r = t >> 4, c4 = (t & 15) * 4;
#pragma unroll
        for (int rr = 0; rr < 4; rr++) {
            const f32x4 v = *(const f32x4*)(src + (long)(k0 + r + rr * 16) * N + n0 + c4);
            st[r + rr * 16][c4 + 0] = v[0];
            st[r + rr * 16][c4 + 1] = v[1];
            st[r + rr * 16][c4 + 2] = v[2];
            st[r + rr * 16][c4 + 3] = v[3];
        }
        __syncthreads();
        const int kc = (t & 7) * 8;
#pragma unroll
        for (int p = 0; p < 2; p++) {
            const int n = p * 32 + (t >> 3);
            bf16x8 o;
#pragma unroll
            for (int e = 0; e < 8; e++) o[e] = (bf16)st[kc + e][n];
            *(bf16x8*)(dst + (long)(n0 + n) * K + k0 + kc) = o;
        }
    } else {
        const int row = bxg - 6912;
        float* ps  = (float*)pmem;       // [4]
        float* pss = (float*)pmem + 4;   // [4]
        const float* xin = x + (long)row * 768;
        float* xr = xf + (long)row * 768;
        float v[3];
#pragma unroll
        for (int i = 0; i < 3; i++) {
            const int c = t + i * 256;
            const float xv = xin[c];
            xr[c] = xv;
            v[i] = xv;
        }
        float s  = v[0] + v[1] + v[2];
        float ss = v[0] * v[0] + v[1] * v[1] + v[2] * v[2];
#pragma unroll
        for (int off = 32; off; off >>= 1) {
            s  += __shfl_xor(s, off);
            ss += __shfl_xor(ss, off);
        }
        const int wv = t >> 6, l = t & 63;
        if (l == 0) { ps[wv] = s; pss[wv] = ss; }
        __syncthreads();
        s  = ps[0] + ps[1] + ps[2] + ps[3];
        ss = pss[0] + pss[1] + pss[2] + pss[3];
        const float mu = s * (1.f / 768.f);
        const float rs = rsqrtf(ss * (1.f / 768.f) - mu * mu + 1e-5f);
        bf16* orow = hout + (long)row * 768;
#pragma unroll
        for (int i = 0; i < 3; i++) {
            const int c = t + i * 256;
            orow[c] = (bf16)((v[i] - mu) * rs * gam[c]);
        }
    }
}

// ---------------------------------------------------------------------------
// Fused residual-reduce + LayerNorm.
// src != null (L0): xf <- src, h = LN(src)
// P0 != null:       xf += LS*(P0+P1+bias), h = LN(xf)
// ---------------------------------------------------------------------------
__global__ __launch_bounds__(256)
void lnres_k(float* __restrict__ xf, const bf16* __restrict__ P0,
             const bf16* __restrict__ P1, const float* __restrict__ bias,
             const float* __restrict__ gam, bf16* __restrict__ out,
             const float* __restrict__ src)
{
    const int row = blockIdx.x, t = threadIdx.x;
    float* xr = xf + (long)row * 768;
    float v[3];
#pragma unroll
    for (int i = 0; i < 3; i++) {
        const int c = t + i * 256;
        float xv;
        if (src) {
            xv = src[(long)row * 768 + c];
            xr[c] = xv;
        } else if (P0) {
            xv = xr[c] + LSCALE * ((float)P0[(long)row * 768 + c] +
                                   (float)P1[(long)row * 768 + c] + bias[c]);
            xr[c] = xv;
        } else {
            xv = xr[c];
        }
        v[i] = xv;
    }
    float s  = v[0] + v[1] + v[2];
    float ss = v[0] * v[0] + v[1] * v[1] + v[2] * v[2];
#pragma unroll
    for (int off = 32; off; off >>= 1) {
        s  += __shfl_xor(s, off);
        ss += __shfl_xor(ss, off);
    }
    __shared__ float ps[4], pss[4];
    const int wv = t >> 6, l = t & 63;
    if (l == 0) { ps[wv] = s; pss[wv] = ss; }
    __syncthreads();
    s  = ps[0] + ps[1] + ps[2] + ps[3];
    ss = pss[0] + pss[1] + pss[2] + pss[3];
    const float mu = s * (1.f / 768.f);
    const float rs = rsqrtf(ss * (1.f / 768.f) - mu * mu + 1e-5f);
    bf16* orow = out + (long)row * 768;
#pragma unroll
    for (int i = 0; i < 3; i++) {
        const int c = t + i * 256;
        orow[c] = (bf16)((v[i] - mu) * rs * gam[c]);
    }
}

// final: d_out = xf + LS*(P0 + P1 + bias)   (f32 out), 4 elems/thread
__global__ __launch_bounds__(256)
void outres_k(const float* __restrict__ xf, const bf16* __restrict__ P0,
              const bf16* __restrict__ P1, const float* __restrict__ bias,
              float* __restrict__ out)
{
    const long i4 = ((long)blockIdx.x * 256 + threadIdx.x) * 4;
    const int c = (int)(i4 % 768);
    const f32x4 xv = *(const f32x4*)(xf + i4);
    const bf16x4 p0 = *(const bf16x4*)(P0 + i4);
    const bf16x4 p1 = *(const bf16x4*)(P1 + i4);
    const f32x4 bv = *(const f32x4*)(bias + c);
    f32x4 o;
#pragma unroll
    for (int e = 0; e < 4; e++)
        o[e] = xv[e] + LSCALE * ((float)p0[e] + (float)p1[e] + bv[e]);
    *(f32x4*)(out + i4) = o;
}

// ---------------------------------------------------------------------------
// talking-heads mix (pre) -> softmax -> mix (post), in place on S.
// v3: v1's low-VGPR LDS structure; CONTIG=1 uses head-contiguous layout
// [b][i][h][j] -> each block touches ONE contiguous 12 KB span (12 h-rows),
// instead of 12 rows scattered 512 KB apart. CONTIG=0 = old layout (fallback).
// Block = (b, i); thread owns j-pair (2t, 2t+1). Accumulation order (h
// ascending) identical to v1 -> numerics unchanged.
// ---------------------------------------------------------------------------
template<int CONTIG>
__global__ __launch_bounds__(256)
void mixsm_k(bf16* __restrict__ S, const float* __restrict__ mp,
             const float* __restrict__ mq)
{
    __shared__ float buf[12][512];
    __shared__ float rds[12];
    const int b = blockIdx.y, i = blockIdx.x, t = threadIdx.x;
    const long pstr = CONTIG ? 512 : 262144;
    bf16* Sb = CONTIG ? S + ((long)b * 512 + i) * 6144
                      : S + ((long)b * 12 * 512 + i) * 512;

    float s0[12], s1[12];
#pragma unroll
    for (int h = 0; h < 12; h++) {
        union { unsigned u; bf16 v[2]; } p;
        p.u = *(const unsigned*)(Sb + h * pstr + 2 * t);
        s0[h] = (float)p.v[0];
        s1[h] = (float)p.v[1];
    }
#pragma unroll
    for (int g = 0; g < 12; g++) {
        float a0 = 0.f, a1 = 0.f;
#pragma unroll
        for (int h = 0; h < 12; h++) {
            const float m = mp[h * 12 + g];     // uniform -> SGPR
            a0 += s0[h] * m;
            a1 += s1[h] * m;
        }
        *(float2*)(&buf[g][2 * t]) = make_float2(a0, a1);
    }
    __syncthreads();

    const int wv = t >> 6, l = t & 63;
    for (int g = wv; g < 12; g += 4) {
        float mx = -3.0e38f;
#pragma unroll
        for (int k = 0; k < 8; k++) mx = fmaxf(mx, buf[g][l + 64 * k]);
#pragma unroll
        for (int off = 32; off; off >>= 1) mx = fmaxf(mx, __shfl_xor(mx, off));
        float sm = 0.f;
#pragma unroll
        for (int k = 0; k < 8; k++) {
            const float e = __expf(buf[g][l + 64 * k] - mx);
            buf[g][l + 64 * k] = e;
            sm += e;
        }
#pragma unroll
        for (int off = 32; off; off >>= 1) sm += __shfl_xor(sm, off);
        if (l == 0) rds[g] = 1.f / sm;
    }
    __syncthreads();

    float e0[12], e1[12];
#pragma unroll
    for (int h = 0; h < 12; h++) {
        const float2 ee = *(const float2*)(&buf[h][2 * t]);
        const float rd = rds[h];
        e0[h] = ee.x * rd;
        e1[h] = ee.y * rd;
    }
#pragma unroll
    for (int g = 0; g < 12; g++) {
        float a0 = 0.f, a1 = 0.f;
#pragma unroll
        for (int h = 0; h < 12; h++) {
            const float m = mq[h * 12 + g];     // uniform -> SGPR
            a0 += e0[h] * m;
            a1 += e1[h] * m;
        }
        union { unsigned u; bf16 v[2]; } p;
        p.v[0] = (bf16)a0;
        p.v[1] = (bf16)a1;
        *(unsigned*)(Sb + g * pstr + 2 * t) = p.u;
    }
}

// ---------------------------------------------------------------------------
extern "C" void kernel_launch(void* const* d_in, const int* in_sizes, int n_in,
                              void* d_out, int out_size, void* d_ws, size_t ws_size,
                              hipStream_t stream)
{
    (void)in_sizes; (void)n_in; (void)out_size;
    const float* x   = (const float*)d_in[0];
    const float* ln1 = (const float*)d_in[1];
    const float* Wq  = (const float*)d_in[2];
    const float* Wkv = (const float*)d_in[3];
    const float* mp  = (const float*)d_in[4];
    const float* mq  = (const float*)d_in[5];
    const float* Wo  = (const float*)d_in[6];
    const float* bo  = (const float*)d_in[7];
    const float* ln2 = (const float*)d_in[8];
    const float* W1  = (const float*)d_in[9];
    const float* b1  = (const float*)d_in[10];
    const float* W2  = (const float*)d_in[11];
    const float* b2  = (const float*)d_in[12];

    char* ws = (char*)d_ws;
    float* xf  = (float*)(ws);               // [4096,768] f32
    bf16* h    = (bf16*)(ws + 12582912);     // [4096,768]; partial plane P0
    bf16* qkv  = (bf16*)(ws + 18874368);     // [4096,2304]; P1(W2)
    bf16* S    = (bf16*)(ws + 37748736);     // scores; MLP mid; P1(Wo)
    bf16* mid  = S;
    bf16* P0   = h;
    bf16* P1w2 = qkv;
    bf16* P1wo = S;
    const long P1W2_OFF = 3145728;           // (qkv - h) in elements
    const long P1WO_OFF = 12582912;          // (S - h) in elements

    const dim3 tb(32, 8);

    if (ws_size >= 150994944ull) {
        // ============ big-workspace path ===================================
        bf16* WtAll = (bf16*)(ws + 88080384);  // [4][7077888]
        bf16* oP    = (bf16*)(ws + 144703488); // [96][512][64] planar attn-o

        // weight transposes (6912 blocks) || L0 lnres (4096 blocks)
        pre_k<<<11008, 256, 0, stream>>>(Wq, Wkv, Wo, W1, W2, WtAll,
                                         x, xf, ln1, h);

        for (int L = 0; L < 4; L++) {
            bf16* WtL = WtAll + (long)L * 7077888;

            // x += LS*(prev-W2 partials + b2_{L-1}) [L>0]; h = LN(x)*ln1
            if (L > 0)
                lnres_k<<<4096, 256, 0, stream>>>(xf, P0, P1w2, b2 + (L - 1) * 768,
                                                  ln1 + L * 768, h, nullptr);

            // qkv = h @ [Wq | Wkv]
            gemm_bt<0><<<dim3(32, 18, 1), 256, 0, stream>>>(
                h, 768, 0, 0, WtL, 768, 0, 0,
                qkv, 2304, 0, 0, 4096, 2304, 768, 1, nullptr, 1.f);

            // scores, head-contiguous S layout [b][i][h][j]: ldc=6144, h-off=512
            gemm_bt<0><<<dim3(4, 4, 96), 256, 0, stream>>>(
                qkv,       2304, 1179648, 64,
                qkv + 768, 2304, 1179648, 64,
                S,         6144, 3145728, 512,
                512, 512, 64, 12, nullptr, 0.125f);

            mixsm_k<1><<<dim3(512, 8), 256, 0, stream>>>(S, mp + L * 144, mq + L * 144);

            // o (planar) = attn @ v, all planes
            gemm_av<1><<<dim3(8, 96), 256, 0, stream>>>(S, qkv, oP);

            // Wo partials: P0/P1wo = o @ Wo (split-K=2, planar A)
            gemm_bt<4, true><<<dim3(32, 6, 2), 256, 0, stream>>>(
                oP, 64, 0, 196608, WtL + 1769472, 768, 0, 384,
                P0, 768, 0, P1WO_OFF, 4096, 768, 384, 2, nullptr, 1.f);

            // x += LS*(P0+P1+bo); h = LN(x)*ln2
            lnres_k<<<4096, 256, 0, stream>>>(xf, P0, P1wo, bo + L * 768,
                                              ln2 + L * 768, h, nullptr);

            // mid = gelu(h @ W1 + b1)
            gemm_bt<1><<<dim3(32, 24, 1), 256, 0, stream>>>(
                h, 768, 0, 0, WtL + 2359296, 768, 0, 0,
                mid, 3072, 0, 0, 4096, 3072, 768, 1, b1 + L * 3072, 1.f);

            // W2 partials: P0/P1w2 = mid @ W2 (split-K=2)
            gemm_bt<4><<<dim3(32, 6, 2), 256, 0, stream>>>(
                mid, 3072, 0, 1536, WtL + 4718592, 3072, 0, 1536,
                P0, 768, 0, P1W2_OFF, 4096, 768, 1536, 2, nullptr, 1.f);
        }
    } else {
        // ============ fallback: previous 67.6 MB two-chunk path ============
        bf16* Wt = (bf16*)(ws + 62914560);

        for (int L = 0; L < 4; L++) {
            tconv_k<<<dim3(24, 24), tb, 0, stream>>>(Wq + (long)L * 589824, Wt, 768, 768);
            tconv_k<<<dim3(48, 24), tb, 0, stream>>>(Wkv + (long)L * 1179648, Wt + 589824, 768, 1536);

            if (L == 0)
                lnres_k<<<4096, 256, 0, stream>>>(xf, nullptr, nullptr, nullptr,
                                                  ln1 + L * 768, h, x);
            else
                lnres_k<<<4096, 256, 0, stream>>>(xf, P0, P1w2, b2 + (L - 1) * 768,
                                                  ln1 + L * 768, h, nullptr);

            gemm_bt<0><<<dim3(32, 18, 1), 256, 0, stream>>>(
                h, 768, 0, 0, Wt, 768, 0, 0,
                qkv, 2304, 0, 0, 4096, 2304, 768, 1, nullptr, 1.f);

            for (int c = 0; c < 2; c++) {
                const long qb = (long)c * 4718592;
                gemm_bt<0><<<dim3(4, 4, 48), 256, 0, stream>>>(
                    qkv + qb,       2304, 1179648, 64,
                    qkv + 768 + qb, 2304, 1179648, 64,
                    S,               512, 3145728, 262144,
                    512, 512, 64, 12, nullptr, 0.125f);

                mixsm_k<0><<<dim3(512, 4), 256, 0, stream>>>(S, mp + L * 144, mq + L * 144);

                gemm_av<0><<<dim3(8, 48), 256, 0, stream>>>(S, qkv + qb, qkv + qb);
            }

            tconv_k<<<dim3(24, 24), tb, 0, stream>>>(Wo + (long)L * 589824, Wt, 768, 768);
            gemm_bt<4><<<dim3(32, 6, 2), 256, 0, stream>>>(
                qkv, 2304, 0, 384, Wt, 768, 0, 384,
                P0, 768, 0, P1WO_OFF, 4096, 768, 384, 2, nullptr, 1.f);

            lnres_k<<<4096, 256, 0, stream>>>(xf, P0, P1wo, bo + L * 768,
                                              ln2 + L * 768, h, nullptr);

            tconv_k<<<dim3(96, 24), tb, 0, stream>>>(W1 + (long)L * 2359296, Wt, 768, 3072);
            gemm_bt<1><<<dim3(32, 24, 1), 256, 0, stream>>>(
                h, 768, 0, 0, Wt, 768, 0, 0,
                mid, 3072, 0, 0, 4096, 3072, 768, 1, b1 + L * 3072, 1.f);

            tconv_k<<<dim3(24, 96), tb, 0, stream>>>(W2 + (long)L * 2359296, Wt, 3072, 768);
            gemm_bt<4><<<dim3(32, 6, 2), 256, 0, stream>>>(
                mid, 3072, 0, 1536, Wt, 3072, 0, 1536,
                P0, 768, 0, P1W2_OFF, 4096, 768, 1536, 2, nullptr, 1.f);
        }
    }

    // d_out = xf + LS*(P0+P1+b2_3)
    outres_k<<<3072, 256, 0, stream>>>(xf, P0, P1w2, b2 + 3 * 768, (float*)d_out);
}

// Round 6
// 858.612 us; speedup vs baseline: 1.0604x; 1.0159x over previous
//
#include <hip/hip_runtime.h>

// ---------------------------------------------------------------------------
// Talking-heads transformer, 4 layers, f32 in/out (bf16 MFMA inside), gfx950.
// B=8 N=512 DIM=768 H=12 DH=64 MLP=3072 DEPTH=4 LS=0.1 EPS=1e-5
//
// BIG-WS layout (needs 151 MB; harness poison-fill shows ws = 256 MiB):
//   xf    f32  [4096,768]    @ 0          residual accumulator
//   h     bf16 [4096,768]    @ 12582912   LN out; also partial plane P0
//   qkv   bf16 [4096,2304]   @ 18874368   q|k|v; P1(W2)
//   S     bf16 [8,512,12,512]@ 37748736   attn scores, HEAD-CONTIGUOUS layout
//                                         [b][i][h][j]; MLP mid; P1(Wo)
//   WtAll bf16 [4*7077888]   @ 88080384   all transposed weights, all layers
//   oP    bf16 [96,512,64]   @ 144703488  attention output, PLANAR per (b,g)
//
// Weight transposes are HBM-pinned (~2.5 TB/s across 4 access-pattern
// variants) -> hidden as RIDER blocks inside MFMA-bound GEMM dispatches.
// Global tile id T = L*1728 + tile; per-layer tiles: [0,432) qkv,
// [432,576) Wo, [576,1152) W1, [1152,1728) W2 (64x64 tiles).
// Rider sets (contiguous, dependency-safe):
//   pre2_k:       T [0,432)      (L0 qkv)       + L0 lnres
//   qkv-L0 GEMM:  T [432,2160)   (L0 rest + L1 qkv)
//   W1-L0 GEMM:   T [2160,3888)  (L1 rest + L2 qkv)
//   W2-L0 GEMM:   T [3888,5616)  (L2 rest + L3 qkv)
//   W1-L1 GEMM:   T [5616,6912)  (L3 rest)
// Fallback (ws < 151 MB): previous 67.6 MB two-chunk layout (old S layout).
// ---------------------------------------------------------------------------

#define LSCALE 0.1f

typedef __bf16 bf16;
typedef __bf16 bf16x8 __attribute__((ext_vector_type(8)));
typedef __bf16 bf16x4 __attribute__((ext_vector_type(4)));
typedef unsigned short ushort4v __attribute__((ext_vector_type(4)));
typedef float  f32x4  __attribute__((ext_vector_type(4)));

// async global->LDS, 16B/lane; LDS dest = wave-uniform base + lane*16B.
__device__ __forceinline__ void g2l16(const void* g, void* l) {
    __builtin_amdgcn_global_load_lds(
        (const __attribute__((address_space(1))) void*)g,
        (__attribute__((address_space(3))) void*)l, 16, 0, 0);
}

// ---------------------------------------------------------------------------
// one 64x64 weight-transpose tile (f32 [K,N] -> bf16 [N,K]), global tile T.
// pmem must be >= 16640 B.
// ---------------------------------------------------------------------------
__device__ __forceinline__ void tconv_tile(int T, int t,
    const float* __restrict__ Wq, const float* __restrict__ Wkv,
    const float* __restrict__ Wo, const float* __restrict__ W1,
    const float* __restrict__ W2, bf16* __restrict__ WtAll, char* pmem)
{
    float (*st)[65] = (float(*)[65])pmem;
    const int L = T / 1728;
    int bx = T - L * 1728;
    bf16* WtL = WtAll + (long)L * 7077888;
    const float* src; bf16* dst; int K, N, ntn;
    if (bx < 144) {
        src = Wq + (long)L * 589824;   dst = WtL;            K = 768;  N = 768;  ntn = 12;
    } else if (bx < 432) {
        bx -= 144;
        src = Wkv + (long)L * 1179648; dst = WtL + 589824;   K = 768;  N = 1536; ntn = 24;
    } else if (bx < 576) {
        bx -= 432;
        src = Wo + (long)L * 589824;   dst = WtL + 1769472;  K = 768;  N = 768;  ntn = 12;
    } else if (bx < 1152) {
        bx -= 576;
        src = W1 + (long)L * 2359296;  dst = WtL + 2359296;  K = 768;  N = 3072; ntn = 48;
    } else {
        bx -= 1152;
        src = W2 + (long)L * 2359296;  dst = WtL + 4718592;  K = 3072; N = 768;  ntn = 12;
    }
    const int n0 = (bx % ntn) * 64, k0 = (bx / ntn) * 64;
    const int r = t >> 4, c4 = (t & 15) * 4;
#pragma unroll
    for (int rr = 0; rr < 4; rr++) {
        const f32x4 v = *(const f32x4*)(src + (long)(k0 + r + rr * 16) * N + n0 + c4);
        st[r + rr * 16][c4 + 0] = v[0];
        st[r + rr * 16][c4 + 1] = v[1];
        st[r + rr * 16][c4 + 2] = v[2];
        st[r + rr * 16][c4 + 3] = v[3];
    }
    __syncthreads();
    const int kc = (t & 7) * 8;
#pragma unroll
    for (int p = 0; p < 2; p++) {
        const int n = p * 32 + (t >> 3);
        bf16x8 o;
#pragma unroll
        for (int e = 0; e < 8; e++) o[e] = (bf16)st[kc + e][n];
        *(bf16x8*)(dst + (long)(n0 + n) * K + k0 + kc) = o;
    }
}

// ---------------------------------------------------------------------------
// GEMM (Bt form): C[M,N] = A[M,K] @ Bt[N,K]^T   (A,Bt bf16, g2l16 staging)
// BK=64 (two 32-k halves per barrier). N % 128 == 0, M % 128 == 0, K % 64 == 0.
// Epilogue: EPI 0 C=acc*scale | EPI 1 C=gelu(acc+bias) | EPI 4 C=acc (partial)
// PLANA: A is planar o [12 g][4096 m][64 d]; per block this is linear lda=64
//        with a (k0>>6)*32768 plane offset per K-tile (g2l16 path unchanged).
// RID:   1-D grid; blocks >= mt*nt*zmod are weight-transpose riders
//        (tiles rbase + idx) hidden under the GEMM's MFMA time.
// C staged through LDS (128x136 bf16) for full-line coalesced 16B stores.
// split-K via z: z1=z/zmod, z2=z%zmod; saz2/sbz2 = k-offsets, scz2 = C offset.
// ---------------------------------------------------------------------------
template<int EPI, bool PLANA = false, bool RID = false>
__global__ __launch_bounds__(256, 2)
void gemm_bt(const bf16* __restrict__ A, int lda, long saz1, long saz2,
             const bf16* __restrict__ Bt, int ldb, long sbz1, long sbz2,
             void* __restrict__ Cv, int ldc, long scz1, long scz2,
             int M, int N, int K, int zmod,
             const float* __restrict__ bias, float scale,
             int mt, int nt, int rbase,
             const float* __restrict__ tWq, const float* __restrict__ tWkv,
             const float* __restrict__ tWo, const float* __restrict__ tW1,
             const float* __restrict__ tW2, bf16* __restrict__ tWt)
{
    __shared__ __align__(16) char smem[35840];   // staging 32KB | bounce 34.8KB
    bf16* As = (bf16*)smem;                      // [2][128*32]
    bf16* Bs = (bf16*)(smem + 16384);            // [2][128*32]
    bf16* Cs = (bf16*)smem;                      // [128][136] (aliases staging)

    int bm, bn, z;
    if constexpr (RID) {
        const int nbg = mt * nt * zmod;
        const int bx = blockIdx.x;
        if (bx >= nbg) {
            tconv_tile(rbase + bx - nbg, threadIdx.x,
                       tWq, tWkv, tWo, tW1, tW2, tWt, smem);
            return;
        }
        bm = bx % mt;
        const int r = bx / mt;
        bn = r % nt;
        z  = r / nt;
    } else {
        bm = blockIdx.x; bn = blockIdx.y; z = blockIdx.z;
    }

    const int z1 = z / zmod, z2 = z - z1 * zmod;
    const bf16* Ab = A  + saz1 * (long)z1 + saz2 * (long)z2;
    const bf16* Bb = Bt + sbz1 * (long)z1 + sbz2 * (long)z2;

    const int m0 = bm * 128, n0 = bn * 128;
    const int tid = threadIdx.x, w = tid >> 6, l = tid & 63;
    const int wr = (w >> 1) * 64, wc = (w & 1) * 64;
    const int lr = l & 15, lq = l >> 4;
    const int srow = l >> 2, scol8 = (l & 3) * 8;

    long abase = 0;
    if constexpr (PLANA)
        abase = (long)(m0 >> 9) * 393216 + (long)((m0 & 511) + w * 32) * 64;

    f32x4 acc[4][4];
#pragma unroll
    for (int i = 0; i < 4; i++)
#pragma unroll
        for (int j = 0; j < 4; j++)
#pragma unroll
            for (int r = 0; r < 4; r++) acc[i][j][r] = 0.f;

    for (int k0 = 0; k0 < K; k0 += 64) {
        const bf16* Ag;
        int ldaa;
        if constexpr (PLANA) {
            Ag = Ab + abase + ((long)(k0 >> 6)) * 32768;
            ldaa = 64;
        } else {
            Ag = Ab + (long)(m0 + w * 32) * lda + k0;
            ldaa = lda;
        }
        const bf16* Bg = Bb + (long)(n0 + w * 32) * ldb + k0;
        g2l16(Ag + (long)srow * ldaa + scol8,             As + w * 1024);
        g2l16(Ag + (long)(srow + 16) * ldaa + scol8,      As + w * 1024 + 512);
        g2l16(Ag + (long)srow * ldaa + 32 + scol8,        As + 4096 + w * 1024);
        g2l16(Ag + (long)(srow + 16) * ldaa + 32 + scol8, As + 4096 + w * 1024 + 512);
        g2l16(Bg + (long)srow * ldb + scol8,             Bs + w * 1024);
        g2l16(Bg + (long)(srow + 16) * ldb + scol8,      Bs + w * 1024 + 512);
        g2l16(Bg + (long)srow * ldb + 32 + scol8,        Bs + 4096 + w * 1024);
        g2l16(Bg + (long)(srow + 16) * ldb + 32 + scol8, Bs + 4096 + w * 1024 + 512);
        __syncthreads();

#pragma unroll
        for (int hh = 0; hh < 2; hh++) {
            bf16x8 fa[4], fb[4];
#pragma unroll
            for (int i = 0; i < 4; i++)
                fa[i] = *(const bf16x8*)(As + hh * 4096 + (wr + i * 16 + lr) * 32 + lq * 8);
#pragma unroll
            for (int i = 0; i < 4; i++)
                fb[i] = *(const bf16x8*)(Bs + hh * 4096 + (wc + i * 16 + lr) * 32 + lq * 8);
#pragma unroll
            for (int mi = 0; mi < 4; mi++)
#pragma unroll
                for (int ni = 0; ni < 4; ni++)
                    acc[mi][ni] = __builtin_amdgcn_mfma_f32_16x16x32_bf16(
                        fa[mi], fb[ni], acc[mi][ni], 0, 0, 0);
        }
        __syncthreads();
    }

    // ---- epilogue: transform, bounce through LDS, coalesced 16B stores ----
#pragma unroll
    for (int ni = 0; ni < 4; ni++) {
        const int col = wc + ni * 16 + lr;
        float bv = 0.f;
        if (EPI == 1) bv = bias[n0 + col];
#pragma unroll
        for (int mi = 0; mi < 4; mi++) {
#pragma unroll
            for (int r = 0; r < 4; r++) {
                const int row = wr + mi * 16 + lq * 4 + r;
                float v = acc[mi][ni][r];
                if (EPI == 0) {
                    v *= scale;
                } else if (EPI == 1) {
                    const float xx = v + bv;
                    const float u  = 0.7978845608f * (xx + 0.044715f * xx * xx * xx);
                    const float th = 1.f - 2.f / (__expf(2.f * u) + 1.f);
                    v = 0.5f * xx * (1.f + th);
                }
                Cs[row * 136 + col] = (bf16)v;
            }
        }
    }
    __syncthreads();

    const long cb = scz1 * (long)z1 + scz2 * (long)z2;
    const int rrow = tid >> 4, cg = tid & 15;
#pragma unroll
    for (int p = 0; p < 8; p++) {
        const int row = p * 16 + rrow;
        const bf16x8 v = *(const bf16x8*)(Cs + row * 136 + cg * 8);
        *(bf16x8*)((bf16*)Cv + cb + (long)(m0 + row) * ldc + n0 + cg * 8) = v;
    }
}

// ---------------------------------------------------------------------------
// AV GEMM: o[b, i, g, d] = sum_j P[b,g-plane,i,j] * v[b,j,g*64+d]
// One block: i-tile 64 x d 64, 4 waves stacked along i (16 rows each).
// PLANO=1: S in head-contiguous layout [b][i][g][j] (row stride 6144);
//          write planar o [z=(b,g)][512 i][64 d] via LDS bounce.
// PLANO=0 (fallback): S old layout [b][g][i][j]; scalar store into q-slot.
// ---------------------------------------------------------------------------
template<int PLANO>
__global__ __launch_bounds__(256, 4)
void gemm_av(const bf16* __restrict__ S, const bf16* __restrict__ qkvc,
             bf16* __restrict__ oc)
{
    __shared__ __align__(16) char av_smem[9728];
    bf16* As  = (bf16*)av_smem;             // [64*32]  4096 B
    bf16* Bst = (bf16*)(av_smem + 4096);    // [64*40]  5120 B
    bf16* Cs  = (bf16*)av_smem;             // [64][68] 8704 B (aliases)

    const int z = blockIdx.y, b = z / 12, g = z - b * 12;
    const bf16* Ab;
    int sld;
    if constexpr (PLANO) {
        Ab = S + (long)b * 3145728 + g * 512;   // [b][i][g][j]
        sld = 6144;
    } else {
        Ab = S + (long)z * 262144;              // [b][g][i][j]
        sld = 512;
    }
    const bf16* Bb = qkvc + (long)b * 1179648 + 1536 + g * 64;  // v

    const int i0 = blockIdx.x * 64;
    const int tid = threadIdx.x, w = tid >> 6, l = tid & 63;
    const int lr = l & 15, lq = l >> 4;
    const int srow = l >> 2, scol8 = (l & 3) * 8;
    const int kp = tid >> 4, dq = tid & 15;   // j-pair, d-quad
    const int kcol = ((((kp >> 2) ^ ((dq >> 1) & 3)) << 3) | ((kp & 3) << 1));

    f32x4 acc[4];
#pragma unroll
    for (int j = 0; j < 4; j++)
#pragma unroll
        for (int r = 0; r < 4; r++) acc[j][r] = 0.f;

    unsigned short* Bw = (unsigned short*)Bst;

    for (int k0 = 0; k0 < 512; k0 += 32) {
        const bf16* Ag = Ab + (long)(i0 + w * 16) * sld + k0;
        g2l16(Ag + (long)srow * sld + scol8, As + w * 512);

        const bf16* Bg = Bb + (long)(k0 + 2 * kp) * 2304 + dq * 4;
        ushort4v u0 = *(const ushort4v*)(Bg);
        ushort4v u1 = *(const ushort4v*)(Bg + 2304);
#pragma unroll
        for (int r = 0; r < 4; r++) {
            unsigned p = (unsigned)u0[r] | ((unsigned)u1[r] << 16);
            *(unsigned*)(Bw + (dq * 4 + r) * 40 + kcol) = p;
        }
        __syncthreads();

        bf16x8 fa = *(const bf16x8*)(As + (w * 16 + lr) * 32 + lq * 8);
        bf16x8 fb[4];
#pragma unroll
        for (int i = 0; i < 4; i++) {
            const int d = i * 16 + lr;
            fb[i] = *(const bf16x8*)(Bst + d * 40 + ((lq ^ ((d >> 3) & 3)) << 3));
        }
#pragma unroll
        for (int ni = 0; ni < 4; ni++)
            acc[ni] = __builtin_amdgcn_mfma_f32_16x16x32_bf16(
                fa, fb[ni], acc[ni], 0, 0, 0);
        __syncthreads();
    }

    if constexpr (PLANO) {
#pragma unroll
        for (int ni = 0; ni < 4; ni++)
#pragma unroll
            for (int r = 0; r < 4; r++)
                Cs[(w * 16 + lq * 4 + r) * 68 + ni * 16 + lr] = (bf16)acc[ni][r];
        __syncthreads();
        const int rr = tid >> 2, c16 = (tid & 3) * 16;
        bf16* orow = oc + ((long)z * 512 + i0 + rr) * 64 + c16;
        *(bf16x8*)(orow)     = *(const bf16x8*)(Cs + rr * 68 + c16);
        *(bf16x8*)(orow + 8) = *(const bf16x8*)(Cs + rr * 68 + c16 + 8);
    } else {
        bf16* Cb = oc + (long)b * 1179648 + g * 64;
#pragma unroll
        for (int ni = 0; ni < 4; ni++) {
            const int gc = ni * 16 + lr;
#pragma unroll
            for (int r = 0; r < 4; r++) {
                const int gr = i0 + w * 16 + lq * 4 + r;
                Cb[(long)gr * 2304 + gc] = (bf16)acc[ni][r];
            }
        }
    }
}

// ---------------------------------------------------------------------------
// transpose+convert: in f32 [K,N] -> out bf16 [N,K].  32x32 tiles.
// (fallback path only)
// ---------------------------------------------------------------------------
__global__ __launch_bounds__(256)
void tconv_k(const float* __restrict__ in, bf16* __restrict__ out,
             int K, int N)
{
    __shared__ float t[32][33];
    const int n0 = blockIdx.x * 32, k0 = blockIdx.y * 32;
    const int x = threadIdx.x, y = threadIdx.y;
#pragma unroll
    for (int yy = 0; yy < 4; yy++)
        t[y + yy * 8][x] = in[(long)(k0 + y + yy * 8) * N + n0 + x];
    __syncthreads();
#pragma unroll
    for (int yy = 0; yy < 4; yy++)
        out[(long)(n0 + y + yy * 8) * K + k0 + x] = (bf16)t[x][y + yy * 8];
}

// ---------------------------------------------------------------------------
// pre2_k: blocks [0,432) = L0 qkv-weight transpose tiles (needed by the very
// next dispatch); blocks [432, 4528) = L0 lnres (xf <- x, h = LN(x)*ln1).
// All other transpose tiles ride inside later GEMM dispatches.
// ---------------------------------------------------------------------------
__global__ __launch_bounds__(256)
void pre2_k(const float* __restrict__ Wq, const float* __restrict__ Wkv,
            const float* __restrict__ Wo, const float* __restrict__ W1,
            const float* __restrict__ W2, bf16* __restrict__ WtAll,
            const float* __restrict__ x, float* __restrict__ xf,
            const float* __restrict__ gam, bf16* __restrict__ hout)
{
    __shared__ __align__(16) char pmem[16640];
    const int bxg = blockIdx.x;
    const int t = threadIdx.x;
    if (bxg < 432) {
        tconv_tile(bxg, t, Wq, Wkv, Wo, W1, W2, WtAll, pmem);
    } else {
        const int row = bxg - 432;
        float* ps  = (float*)pmem;       // [4]
        float* pss = (float*)pmem + 4;   // [4]
        const float* xin = x + (long)row * 768;
        float* xr = xf + (long)row * 768;
        float v[3];
#pragma unroll
        for (int i = 0; i < 3; i++) {
            const int c = t + i * 256;
            const float xv = xin[c];
            xr[c] = xv;
            v[i] = xv;
        }
        float s  = v[0] + v[1] + v[2];
        float ss = v[0] * v[0] + v[1] * v[1] + v[2] * v[2];
#pragma unroll
        for (int off = 32; off; off >>= 1) {
            s  += __shfl_xor(s, off);
            ss += __shfl_xor(ss, off);
        }
        const int wv = t >> 6, l = t & 63;
        if (l == 0) { ps[wv] = s; pss[wv] = ss; }
        __syncthreads();
        s  = ps[0] + ps[1] + ps[2] + ps[3];
        ss = pss[0] + pss[1] + pss[2] + pss[3];
        const float mu = s * (1.f / 768.f);
        const float rs = rsqrtf(ss * (1.f / 768.f) - mu * mu + 1e-5f);
        bf16* orow = hout + (long)row * 768;
#pragma unroll
        for (int i = 0; i < 3; i++) {
            const int c = t + i * 256;
            orow[c] = (bf16)((v[i] - mu) * rs * gam[c]);
        }
    }
}

// ---------------------------------------------------------------------------
// Fused residual-reduce + LayerNorm.
// src != null (L0): xf <- src, h = LN(src)
// P0 != null:       xf += LS*(P0+P1+bias), h = LN(xf)
// ---------------------------------------------------------------------------
__global__ __launch_bounds__(256)
void lnres_k(float* __restrict__ xf, const bf16* __restrict__ P0,
             const bf16* __restrict__ P1, const float* __restrict__ bias,
             const float* __restrict__ gam, bf16* __restrict__ out,
             const float* __restrict__ src)
{
    const int row = blockIdx.x, t = threadIdx.x;
    float* xr = xf + (long)row * 768;
    float v[3];
#pragma unroll
    for (int i = 0; i < 3; i++) {
        const int c = t + i * 256;
        float xv;
        if (src) {
            xv = src[(long)row * 768 + c];
            xr[c] = xv;
        } else if (P0) {
            xv = xr[c] + LSCALE * ((float)P0[(long)row * 768 + c] +
                                   (float)P1[(long)row * 768 + c] + bias[c]);
            xr[c] = xv;
        } else {
            xv = xr[c];
        }
        v[i] = xv;
    }
    float s  = v[0] + v[1] + v[2];
    float ss = v[0] * v[0] + v[1] * v[1] + v[2] * v[2];
#pragma unroll
    for (int off = 32; off; off >>= 1) {
        s  += __shfl_xor(s, off);
        ss += __shfl_xor(ss, off);
    }
    __shared__ float ps[4], pss[4];
    const int wv = t >> 6, l = t & 63;
    if (l == 0) { ps[wv] = s; pss[wv] = ss; }
    __syncthreads();
    s  = ps[0] + ps[1] + ps[2] + ps[3];
    ss = pss[0] + pss[1] + pss[2] + pss[3];
    const float mu = s * (1.f / 768.f);
    const float rs = rsqrtf(ss * (1.f / 768.f) - mu * mu + 1e-5f);
    bf16* orow = out + (long)row * 768;
#pragma unroll
    for (int i = 0; i < 3; i++) {
        const int c = t + i * 256;
        orow[c] = (bf16)((v[i] - mu) * rs * gam[c]);
    }
}

// final: d_out = xf + LS*(P0 + P1 + bias)   (f32 out), 4 elems/thread
__global__ __launch_bounds__(256)
void outres_k(const float* __restrict__ xf, const bf16* __restrict__ P0,
              const bf16* __restrict__ P1, const float* __restrict__ bias,
              float* __restrict__ out)
{
    const long i4 = ((long)blockIdx.x * 256 + threadIdx.x) * 4;
    const int c = (int)(i4 % 768);
    const f32x4 xv = *(const f32x4*)(xf + i4);
    const bf16x4 p0 = *(const bf16x4*)(P0 + i4);
    const bf16x4 p1 = *(const bf16x4*)(P1 + i4);
    const f32x4 bv = *(const f32x4*)(bias + c);
    f32x4 o;
#pragma unroll
    for (int e = 0; e < 4; e++)
        o[e] = xv[e] + LSCALE * ((float)p0[e] + (float)p1[e] + bv[e]);
    *(f32x4*)(out + i4) = o;
}

// ---------------------------------------------------------------------------
// talking-heads mix (pre) -> softmax -> mix (post), in place on S.
// CONTIG=1: head-contiguous layout [b][i][h][j] -> each block touches ONE
// contiguous 12 KB span. CONTIG=0 = old layout (fallback).
// Block = (b, i); thread owns j-pair (2t, 2t+1).
// ---------------------------------------------------------------------------
template<int CONTIG>
__global__ __launch_bounds__(256)
void mixsm_k(bf16* __restrict__ S, const float* __restrict__ mp,
             const float* __restrict__ mq)
{
    __shared__ float buf[12][512];
    __shared__ float rds[12];
    const int b = blockIdx.y, i = blockIdx.x, t = threadIdx.x;
    const long pstr = CONTIG ? 512 : 262144;
    bf16* Sb = CONTIG ? S + ((long)b * 512 + i) * 6144
                      : S + ((long)b * 12 * 512 + i) * 512;

    float s0[12], s1[12];
#pragma unroll
    for (int h = 0; h < 12; h++) {
        union { unsigned u; bf16 v[2]; } p;
        p.u = *(const unsigned*)(Sb + h * pstr + 2 * t);
        s0[h] = (float)p.v[0];
        s1[h] = (float)p.v[1];
    }
#pragma unroll
    for (int g = 0; g < 12; g++) {
        float a0 = 0.f, a1 = 0.f;
#pragma unroll
        for (int h = 0; h < 12; h++) {
            const float m = mp[h * 12 + g];     // uniform -> SGPR
            a0 += s0[h] * m;
            a1 += s1[h] * m;
        }
        *(float2*)(&buf[g][2 * t]) = make_float2(a0, a1);
    }
    __syncthreads();

    const int wv = t >> 6, l = t & 63;
    for (int g = wv; g < 12; g += 4) {
        float mx = -3.0e38f;
#pragma unroll
        for (int k = 0; k < 8; k++) mx = fmaxf(mx, buf[g][l + 64 * k]);
#pragma unroll
        for (int off = 32; off; off >>= 1) mx = fmaxf(mx, __shfl_xor(mx, off));
        float sm = 0.f;
#pragma unroll
        for (int k = 0; k < 8; k++) {
            const float e = __expf(buf[g][l + 64 * k] - mx);
            buf[g][l + 64 * k] = e;
            sm += e;
        }
#pragma unroll
        for (int off = 32; off; off >>= 1) sm += __shfl_xor(sm, off);
        if (l == 0) rds[g] = 1.f / sm;
    }
    __syncthreads();

    float e0[12], e1[12];
#pragma unroll
    for (int h = 0; h < 12; h++) {
        const float2 ee = *(const float2*)(&buf[h][2 * t]);
        const float rd = rds[h];
        e0[h] = ee.x * rd;
        e1[h] = ee.y * rd;
    }
#pragma unroll
    for (int g = 0; g < 12; g++) {
        float a0 = 0.f, a1 = 0.f;
#pragma unroll
        for (int h = 0; h < 12; h++) {
            const float m = mq[h * 12 + g];     // uniform -> SGPR
            a0 += e0[h] * m;
            a1 += e1[h] * m;
        }
        union { unsigned u; bf16 v[2]; } p;
        p.v[0] = (bf16)a0;
        p.v[1] = (bf16)a1;
        *(unsigned*)(Sb + g * pstr + 2 * t) = p.u;
    }
}

// ---------------------------------------------------------------------------
extern "C" void kernel_launch(void* const* d_in, const int* in_sizes, int n_in,
                              void* d_out, int out_size, void* d_ws, size_t ws_size,
                              hipStream_t stream)
{
    (void)in_sizes; (void)n_in; (void)out_size;
    const float* x   = (const float*)d_in[0];
    const float* ln1 = (const float*)d_in[1];
    const float* Wq  = (const float*)d_in[2];
    const float* Wkv = (const float*)d_in[3];
    const float* mp  = (const float*)d_in[4];
    const float* mq  = (const float*)d_in[5];
    const float* Wo  = (const float*)d_in[6];
    const float* bo  = (const float*)d_in[7];
    const float* ln2 = (const float*)d_in[8];
    const float* W1  = (const float*)d_in[9];
    const float* b1  = (const float*)d_in[10];
    const float* W2  = (const float*)d_in[11];
    const float* b2  = (const float*)d_in[12];

    char* ws = (char*)d_ws;
    float* xf  = (float*)(ws);               // [4096,768] f32
    bf16* h    = (bf16*)(ws + 12582912);     // [4096,768]; partial plane P0
    bf16* qkv  = (bf16*)(ws + 18874368);     // [4096,2304]; P1(W2)
    bf16* S    = (bf16*)(ws + 37748736);     // scores; MLP mid; P1(Wo)
    bf16* mid  = S;
    bf16* P0   = h;
    bf16* P1w2 = qkv;
    bf16* P1wo = S;
    const long P1W2_OFF = 3145728;           // (qkv - h) in elements
    const long P1WO_OFF = 12582912;          // (S - h) in elements

    const dim3 tb(32, 8);

    if (ws_size >= 150994944ull) {
        // ============ big-workspace path ===================================
        bf16* WtAll = (bf16*)(ws + 88080384);  // [4][7077888]
        bf16* oP    = (bf16*)(ws + 144703488); // [96][512][64] planar attn-o

        // L0 qkv-weight transposes (432) || L0 lnres (4096)
        pre2_k<<<4528, 256, 0, stream>>>(Wq, Wkv, Wo, W1, W2, WtAll,
                                         x, xf, ln1, h);

        for (int L = 0; L < 4; L++) {
            bf16* WtL = WtAll + (long)L * 7077888;

            // x += LS*(prev-W2 partials + b2_{L-1}) [L>0]; h = LN(x)*ln1
            if (L > 0)
                lnres_k<<<4096, 256, 0, stream>>>(xf, P0, P1w2, b2 + (L - 1) * 768,
                                                  ln1 + L * 768, h, nullptr);

            // qkv = h @ [Wq | Wkv]; L0 hosts riders T [432,2160)
            if (L == 0)
                gemm_bt<0, false, true><<<576 + 1728, 256, 0, stream>>>(
                    h, 768, 0, 0, WtL, 768, 0, 0,
                    qkv, 2304, 0, 0, 4096, 2304, 768, 1, nullptr, 1.f,
                    32, 18, 432, Wq, Wkv, Wo, W1, W2, WtAll);
            else
                gemm_bt<0><<<dim3(32, 18, 1), 256, 0, stream>>>(
                    h, 768, 0, 0, WtL, 768, 0, 0,
                    qkv, 2304, 0, 0, 4096, 2304, 768, 1, nullptr, 1.f,
                    0, 0, 0, nullptr, nullptr, nullptr, nullptr, nullptr, nullptr);

            // scores, head-contiguous S layout [b][i][h][j]: ldc=6144, h-off=512
            gemm_bt<0><<<dim3(4, 4, 96), 256, 0, stream>>>(
                qkv,       2304, 1179648, 64,
                qkv + 768, 2304, 1179648, 64,
                S,         6144, 3145728, 512,
                512, 512, 64, 12, nullptr, 0.125f,
                0, 0, 0, nullptr, nullptr, nullptr, nullptr, nullptr, nullptr);

            mixsm_k<1><<<dim3(512, 8), 256, 0, stream>>>(S, mp + L * 144, mq + L * 144);

            // o (planar) = attn @ v, all planes
            gemm_av<1><<<dim3(8, 96), 256, 0, stream>>>(S, qkv, oP);

            // Wo partials: P0/P1wo = o @ Wo (split-K=2, planar A)
            gemm_bt<4, true><<<dim3(32, 6, 2), 256, 0, stream>>>(
                oP, 64, 0, 196608, WtL + 1769472, 768, 0, 384,
                P0, 768, 0, P1WO_OFF, 4096, 768, 384, 2, nullptr, 1.f,
                0, 0, 0, nullptr, nullptr, nullptr, nullptr, nullptr, nullptr);

            // x += LS*(P0+P1+bo); h = LN(x)*ln2
            lnres_k<<<4096, 256, 0, stream>>>(xf, P0, P1wo, bo + L * 768,
                                              ln2 + L * 768, h, nullptr);

            // mid = gelu(h @ W1 + b1); L0 riders [2160,3888), L1 riders [5616,6912)
            if (L == 0)
                gemm_bt<1, false, true><<<768 + 1728, 256, 0, stream>>>(
                    h, 768, 0, 0, WtL + 2359296, 768, 0, 0,
                    mid, 3072, 0, 0, 4096, 3072, 768, 1, b1 + L * 3072, 1.f,
                    32, 24, 2160, Wq, Wkv, Wo, W1, W2, WtAll);
            else if (L == 1)
                gemm_bt<1, false, true><<<768 + 1296, 256, 0, stream>>>(
                    h, 768, 0, 0, WtL + 2359296, 768, 0, 0,
                    mid, 3072, 0, 0, 4096, 3072, 768, 1, b1 + L * 3072, 1.f,
                    32, 24, 5616, Wq, Wkv, Wo, W1, W2, WtAll);
            else
                gemm_bt<1><<<dim3(32, 24, 1), 256, 0, stream>>>(
                    h, 768, 0, 0, WtL + 2359296, 768, 0, 0,
                    mid, 3072, 0, 0, 4096, 3072, 768, 1, b1 + L * 3072, 1.f,
                    0, 0, 0, nullptr, nullptr, nullptr, nullptr, nullptr, nullptr);

            // W2 partials: P0/P1w2 = mid @ W2 (split-K=2); L0 riders [3888,5616)
            if (L == 0)
                gemm_bt<4, false, true><<<384 + 1728, 256, 0, stream>>>(
                    mid, 3072, 0, 1536, WtL + 4718592, 3072, 0, 1536,
                    P0, 768, 0, P1W2_OFF, 4096, 768, 1536, 2, nullptr, 1.f,
                    32, 6, 3888, Wq, Wkv, Wo, W1, W2, WtAll);
            else
                gemm_bt<4><<<dim3(32, 6, 2), 256, 0, stream>>>(
                    mid, 3072, 0, 1536, WtL + 4718592, 3072, 0, 1536,
                    P0, 768, 0, P1W2_OFF, 4096, 768, 1536, 2, nullptr, 1.f,
                    0, 0, 0, nullptr, nullptr, nullptr, nullptr, nullptr, nullptr);
        }
    } else {
        // ============ fallback: previous 67.6 MB two-chunk path ============
        bf16* Wt = (bf16*)(ws + 62914560);

        for (int L = 0; L < 4; L++) {
            tconv_k<<<dim3(24, 24), tb, 0, stream>>>(Wq + (long)L * 589824, Wt, 768, 768);
            tconv_k<<<dim3(48, 24), tb, 0, stream>>>(Wkv + (long)L * 1179648, Wt + 589824, 768, 1536);

            if (L == 0)
                lnres_k<<<4096, 256, 0, stream>>>(xf, nullptr, nullptr, nullptr,
                                                  ln1 + L * 768, h, x);
            else
                lnres_k<<<4096, 256, 0, stream>>>(xf, P0, P1w2, b2 + (L - 1) * 768,
                                                  ln1 + L * 768, h, nullptr);

            gemm_bt<0><<<dim3(32, 18, 1), 256, 0, stream>>>(
                h, 768, 0, 0, Wt, 768, 0, 0,
                qkv, 2304, 0, 0, 4096, 2304, 768, 1, nullptr, 1.f,
                0, 0, 0, nullptr, nullptr, nullptr, nullptr, nullptr, nullptr);

            for (int c = 0; c < 2; c++) {
                const long qb = (long)c * 4718592;
                gemm_bt<0><<<dim3(4, 4, 48), 256, 0, stream>>>(
                    qkv + qb,       2304, 1179648, 64,
                    qkv + 768 + qb, 2304, 1179648, 64,
                    S,               512, 3145728, 262144,
                    512, 512, 64, 12, nullptr, 0.125f,
                    0, 0, 0, nullptr, nullptr, nullptr, nullptr, nullptr, nullptr);

                mixsm_k<0><<<dim3(512, 4), 256, 0, stream>>>(S, mp + L * 144, mq + L * 144);

                gemm_av<0><<<dim3(8, 48), 256, 0, stream>>>(S, qkv + qb, qkv + qb);
            }

            tconv_k<<<dim3(24, 24), tb, 0, stream>>>(Wo + (long)L * 589824, Wt, 768, 768);
            gemm_bt<4><<<dim3(32, 6, 2), 256, 0, stream>>>(
                qkv, 2304, 0, 384, Wt, 768, 0, 384,
                P0, 768, 0, P1WO_OFF, 4096, 768, 384, 2, nullptr, 1.f,
                0, 0, 0, nullptr, nullptr, nullptr, nullptr, nullptr, nullptr);

            lnres_k<<<4096, 256, 0, stream>>>(xf, P0, P1wo, bo + L * 768,
                                              ln2 + L * 768, h, nullptr);

            tconv_k<<<dim3(96, 24), tb, 0, stream>>>(W1 + (long)L * 2359296, Wt, 768, 3072);
            gemm_bt<1><<<dim3(32, 24, 1), 256, 0, stream>>>(
                h, 768, 0, 0, Wt, 768, 0, 0,
                mid, 3072, 0, 0, 4096, 3072, 768, 1, b1 + L * 3072, 1.f,
                0, 0, 0, nullptr, nullptr, nullptr, nullptr, nullptr, nullptr);

            tconv_k<<<dim3(24, 96), tb, 0, stream>>>(W2 + (long)L * 2359296, Wt, 3072, 768);
            gemm_bt<4><<<dim3(32, 6, 2), 256, 0, stream>>>(
                mid, 3072, 0, 1536, Wt, 3072, 0, 1536,
                P0, 768, 0, P1W2_OFF, 4096, 768, 1536, 2, nullptr, 1.f,
                0, 0, 0, nullptr, nullptr, nullptr, nullptr, nullptr, nullptr);
        }
    }

    // d_out = xf + LS*(P0+P1+b2_3)
    outres_k<<<3072, 256, 0, stream>>>(xf, P0, P1w2, b2 + 3 * 768, (float*)d_out);
}